// Round 6
// baseline (936.298 us; speedup 1.0000x reference)
//
#include <hip/hip_runtime.h>

#define NB 4
#define NS 2048
#define ND 512
#define NH 8
#define NDK 64
#define LN_EPS 1e-5f
#define SCLAMP 80.0f

typedef __attribute__((ext_vector_type(8))) short short8;
typedef __attribute__((ext_vector_type(4))) float f32x4;

__device__ inline short f2bf(float x) {
    unsigned u = __builtin_bit_cast(unsigned, x);
    unsigned r = (u + 0x7FFFu + ((u >> 16) & 1u)) >> 16;
    return (short)r;
}
__device__ inline float bf2f(short h) {
    unsigned u = ((unsigned)(unsigned short)h) << 16;
    return __builtin_bit_cast(float, u);
}

// ---------------------------------------------------------------------------
// Projection GEMM core (f32, 128x128 tile, BK=32, 8x8 micro).
// MODE 0: write bf16 hi+lo in [B,H,S,DK] layout (for Q,K -> MFMA frags)
// MODE 1: write bf16 V-transposed [B,H,DK,S] (for PV B-frags)
// ---------------------------------------------------------------------------
template<int MODE>
__global__ __launch_bounds__(256) void k_proj_t(
    const float* __restrict__ X, const float* __restrict__ W,
    const float* __restrict__ bias,
    short* __restrict__ outh, short* __restrict__ outl)
{
    __shared__ float As[32][132];
    __shared__ float Bs[32][132];
    const int tid = threadIdx.x;
    const int tx = tid & 15, ty = tid >> 4;
    const int row0 = blockIdx.y * 128;
    const int col0 = blockIdx.x * 128;
    const int sr = tid >> 3;
    const int sc = tid & 7;

    float acc[8][8] = {};

    for (int k0 = 0; k0 < ND; k0 += 32) {
#pragma unroll
        for (int i = 0; i < 4; ++i) {
            int r = sr + 32 * i;
            float4 a = *(const float4*)&X[(size_t)(row0 + r) * ND + k0 + sc * 4];
            As[sc*4+0][r]=a.x; As[sc*4+1][r]=a.y; As[sc*4+2][r]=a.z; As[sc*4+3][r]=a.w;
            float4 b = *(const float4*)&W[(size_t)(col0 + r) * ND + k0 + sc * 4];
            Bs[sc*4+0][r]=b.x; Bs[sc*4+1][r]=b.y; Bs[sc*4+2][r]=b.z; Bs[sc*4+3][r]=b.w;
        }
        __syncthreads();
#pragma unroll
        for (int kk = 0; kk < 32; ++kk) {
            float a[8], b[8];
#pragma unroll
            for (int i = 0; i < 8; ++i) a[i] = As[kk][ty * 8 + i];
#pragma unroll
            for (int j = 0; j < 8; ++j) b[j] = Bs[kk][tx * 8 + j];
#pragma unroll
            for (int i = 0; i < 8; ++i)
#pragma unroll
                for (int j = 0; j < 8; ++j)
                    acc[i][j] += a[i] * b[j];
        }
        __syncthreads();
    }

    if (MODE == 0) {
#pragma unroll
        for (int i = 0; i < 8; ++i) {
            int r = row0 + ty * 8 + i;
            int b_ = r >> 11, s_ = r & (NS - 1);
            int c0 = col0 + tx * 8;
            int h_ = c0 >> 6, dk = c0 & (NDK - 1);
            short8 hh, ll;
#pragma unroll
            for (int j = 0; j < 8; ++j) {
                float x = acc[i][j] + bias[c0 + j];
                short hb = f2bf(x);
                hh[j] = hb;
                ll[j] = f2bf(x - bf2f(hb));
            }
            size_t idx = (((size_t)b_ * NH + h_) * NS + s_) * NDK + dk;
            *(short8*)&outh[idx] = hh;
            *(short8*)&outl[idx] = ll;
        }
    } else {
        int r0 = row0 + ty * 8;
        int b_ = r0 >> 11, s0 = r0 & (NS - 1);
#pragma unroll
        for (int j = 0; j < 8; ++j) {
            int c = col0 + tx * 8 + j;
            int h_ = c >> 6, dk = c & (NDK - 1);
            short8 vv;
#pragma unroll
            for (int i = 0; i < 8; ++i) vv[i] = f2bf(acc[i][j] + bias[c]);
            *(short8*)&outh[(((size_t)b_ * NH + h_) * NDK + dk) * NS + s0] = vv;
        }
    }
}

// ---------------------------------------------------------------------------
// XCD-clustered remap for attention grids (1024 blocks = 32 bh x 32 rowtiles).
// All row-tiles of a given bh land on the same XCD (wg % 8 == bh % 8),
// so K/V for that bh stay resident in one L2 (3 MB < 4 MB).
// ---------------------------------------------------------------------------
__device__ inline void att_decode(int wg, int& bh, int& rt) {
    rt = (wg >> 3) & 31;
    bh = (wg & 7) + ((wg >> 8) << 3);
}

// ---------------------------------------------------------------------------
// Pass A: row sums of exp(s). No max subtraction (scores bounded, clamp
// identical in both passes). Wave = 16 rows x all 2048 cols, 64-col chunks.
// ---------------------------------------------------------------------------
__global__ __launch_bounds__(256) void k_stats(
    const short* __restrict__ qh, const short* __restrict__ ql,
    const short* __restrict__ kh, const short* __restrict__ kl,
    float* __restrict__ iLrow)
{
    const int tid = threadIdx.x;
    const int w = tid >> 6, lane = tid & 63;
    const int lr = lane & 15, lg = lane >> 4;
    int bh, rt;
    att_decode(blockIdx.x, bh, rt);
    const int row0 = rt * 64 + w * 16;
    const size_t base = (size_t)bh * NS * NDK;

    short8 ah[2], al[2];
#pragma unroll
    for (int ks = 0; ks < 2; ++ks) {
        size_t idx = base + (size_t)(row0 + lr) * NDK + ks * 32 + lg * 8;
        ah[ks] = *(const short8*)&qh[idx];
        al[ks] = *(const short8*)&ql[idx];
    }

    float lsum[4] = {0.f, 0.f, 0.f, 0.f};

#pragma unroll 2
    for (int c = 0; c < NS / 64; ++c) {
        const int col0 = c * 64;
        short8 kfh[4][2], kfl[4][2];
#pragma unroll
        for (int cs = 0; cs < 4; ++cs)
#pragma unroll
            for (int ks = 0; ks < 2; ++ks) {
                size_t idx = base + (size_t)(col0 + cs * 16 + lr) * NDK + ks * 32 + lg * 8;
                kfh[cs][ks] = *(const short8*)&kh[idx];
                kfl[cs][ks] = *(const short8*)&kl[idx];
            }
        f32x4 sa[4] = {};
#pragma unroll
        for (int cs = 0; cs < 4; ++cs)
#pragma unroll
            for (int ks = 0; ks < 2; ++ks) {
                sa[cs] = __builtin_amdgcn_mfma_f32_16x16x32_bf16(ah[ks], kfh[cs][ks], sa[cs], 0, 0, 0);
                sa[cs] = __builtin_amdgcn_mfma_f32_16x16x32_bf16(ah[ks], kfl[cs][ks], sa[cs], 0, 0, 0);
                sa[cs] = __builtin_amdgcn_mfma_f32_16x16x32_bf16(al[ks], kfh[cs][ks], sa[cs], 0, 0, 0);
            }
#pragma unroll
        for (int cs = 0; cs < 4; ++cs)
#pragma unroll
            for (int r = 0; r < 4; ++r)
                lsum[r] += __expf(fminf(sa[cs][r], SCLAMP));
    }

#pragma unroll
    for (int r = 0; r < 4; ++r) {
#pragma unroll
        for (int off = 1; off < 16; off <<= 1)
            lsum[r] += __shfl_xor(lsum[r], off);
    }
    if (lr == 0) {
#pragma unroll
        for (int r = 0; r < 4; ++r)
            iLrow[(size_t)bh * NS + row0 + lg * 4 + r] = 1.0f / lsum[r];
    }
}

// ---------------------------------------------------------------------------
// Pass B: recompute scores, p = exp(min(s,80))*iL. p goes through a per-wave
// LDS f32 tile; the attn store phase reads it ROW-MAJOR so each store
// instruction writes 4 rows x 256B fully contiguous. All chunk loads issue
// before the stores (counted vmcnt can skip the store drain). PV A-frags
// come from the same LDS tile; B-frags from bf16 V^T.
// ---------------------------------------------------------------------------
__global__ __launch_bounds__(256) void k_pv(
    const short* __restrict__ qh, const short* __restrict__ ql,
    const short* __restrict__ kh, const short* __restrict__ kl,
    const short* __restrict__ vtb, const float* __restrict__ iLrow,
    float* __restrict__ attn, short* __restrict__ ctxb)
{
    __shared__ float plds[4][16][68];
    const int tid = threadIdx.x;
    const int w = tid >> 6, lane = tid & 63;
    const int lr = lane & 15, lg = lane >> 4;
    int bh, rt;
    att_decode(blockIdx.x, bh, rt);
    const int row0 = rt * 64 + w * 16;
    const size_t base = (size_t)bh * NS * NDK;
    const short* vb = vtb + (size_t)bh * NDK * NS;
    float* ab = attn + (size_t)bh * NS * NS;
    const int srow = lane >> 4;        // store phase: row = rp*4 + srow
    const int scol = (lane & 15) * 4;  // store phase: 16 lanes x 16B = 256B/row

    short8 ah[2], al[2];
#pragma unroll
    for (int ks = 0; ks < 2; ++ks) {
        size_t idx = base + (size_t)(row0 + lr) * NDK + ks * 32 + lg * 8;
        ah[ks] = *(const short8*)&qh[idx];
        al[ks] = *(const short8*)&ql[idx];
    }
    float iLr[4];
#pragma unroll
    for (int r = 0; r < 4; ++r)
        iLr[r] = iLrow[(size_t)bh * NS + row0 + lg * 4 + r];

    f32x4 vacc[4] = {};

#pragma unroll 2
    for (int c = 0; c < NS / 64; ++c) {
        const int col0 = c * 64;
        // ---- all global loads for this chunk, issued up front ----
        short8 kfh[4][2], kfl[4][2], vf[2][4];
#pragma unroll
        for (int cs = 0; cs < 4; ++cs)
#pragma unroll
            for (int ks = 0; ks < 2; ++ks) {
                size_t idx = base + (size_t)(col0 + cs * 16 + lr) * NDK + ks * 32 + lg * 8;
                kfh[cs][ks] = *(const short8*)&kh[idx];
                kfl[cs][ks] = *(const short8*)&kl[idx];
            }
#pragma unroll
        for (int k2 = 0; k2 < 2; ++k2)
#pragma unroll
            for (int d = 0; d < 4; ++d)
                vf[k2][d] = *(const short8*)&vb[(size_t)(d * 16 + lr) * NS + col0 + k2 * 32 + lg * 8];

        // ---- scores (same MFMA order as k_stats -> bitwise-identical s) ----
        f32x4 sa[4] = {};
#pragma unroll
        for (int cs = 0; cs < 4; ++cs)
#pragma unroll
            for (int ks = 0; ks < 2; ++ks) {
                sa[cs] = __builtin_amdgcn_mfma_f32_16x16x32_bf16(ah[ks], kfh[cs][ks], sa[cs], 0, 0, 0);
                sa[cs] = __builtin_amdgcn_mfma_f32_16x16x32_bf16(ah[ks], kfl[cs][ks], sa[cs], 0, 0, 0);
                sa[cs] = __builtin_amdgcn_mfma_f32_16x16x32_bf16(al[ks], kfh[cs][ks], sa[cs], 0, 0, 0);
            }

        // ---- normalize into wave-private LDS tile ----
#pragma unroll
        for (int cs = 0; cs < 4; ++cs)
#pragma unroll
            for (int r = 0; r < 4; ++r) {
                float p = __expf(fminf(sa[cs][r], SCLAMP)) * iLr[r];
                plds[w][lg * 4 + r][cs * 16 + lr] = p;
            }

        // ---- coalesced attn stores: 4 rows x 256B contiguous per instr ----
#pragma unroll
        for (int rp = 0; rp < 4; ++rp) {
            int row = rp * 4 + srow;
            float4 pv = *(const float4*)&plds[w][row][scol];
            *(float4*)&ab[(size_t)(row0 + row) * NS + col0 + scol] = pv;
        }

        // ---- PV: A-frags from LDS tile, B-frags = vf ----
#pragma unroll
        for (int k2 = 0; k2 < 2; ++k2) {
            float4 q0 = *(const float4*)&plds[w][lr][k2 * 32 + lg * 8];
            float4 q1 = *(const float4*)&plds[w][lr][k2 * 32 + lg * 8 + 4];
            short8 pa;
            pa[0] = f2bf(q0.x); pa[1] = f2bf(q0.y); pa[2] = f2bf(q0.z); pa[3] = f2bf(q0.w);
            pa[4] = f2bf(q1.x); pa[5] = f2bf(q1.y); pa[6] = f2bf(q1.z); pa[7] = f2bf(q1.w);
#pragma unroll
            for (int d = 0; d < 4; ++d)
                vacc[d] = __builtin_amdgcn_mfma_f32_16x16x32_bf16(pa, vf[k2][d], vacc[d], 0, 0, 0);
        }
    }

    const int b_ = bh >> 3, h_ = bh & 7;
#pragma unroll
    for (int d = 0; d < 4; ++d)
#pragma unroll
        for (int r = 0; r < 4; ++r) {
            int row = row0 + lg * 4 + r;
            ctxb[((size_t)b_ * NS + row) * ND + h_ * NDK + d * 16 + lr] = f2bf(vacc[d][r]);
        }
}

// ---------------------------------------------------------------------------
// out[r][c] = sum_k ctx_bf16[r][k] * Wo[c][k] + bo[c] + residual[r][c]
// ---------------------------------------------------------------------------
__global__ __launch_bounds__(256) void k_outproj(
    const short* __restrict__ Xc, const float* __restrict__ W,
    const float* __restrict__ bias, const float* __restrict__ Qin,
    float* __restrict__ out)
{
    __shared__ float As[32][132];
    __shared__ float Bs[32][132];
    const int tid = threadIdx.x;
    const int tx = tid & 15, ty = tid >> 4;
    const int row0 = blockIdx.y * 128;
    const int col0 = blockIdx.x * 128;
    const int sr = tid >> 3;
    const int sc = tid & 7;

    float acc[8][8] = {};

    for (int k0 = 0; k0 < ND; k0 += 32) {
#pragma unroll
        for (int i = 0; i < 2; ++i) {
            int ch = tid + 256 * i;
            int r = ch >> 2, kc = ch & 3;
            short8 a8 = *(const short8*)&Xc[(size_t)(row0 + r) * ND + k0 + kc * 8];
#pragma unroll
            for (int j = 0; j < 8; ++j) As[kc * 8 + j][r] = bf2f(a8[j]);
        }
#pragma unroll
        for (int i = 0; i < 4; ++i) {
            int r = sr + 32 * i;
            float4 b = *(const float4*)&W[(size_t)(col0 + r) * ND + k0 + sc * 4];
            Bs[sc*4+0][r]=b.x; Bs[sc*4+1][r]=b.y; Bs[sc*4+2][r]=b.z; Bs[sc*4+3][r]=b.w;
        }
        __syncthreads();
#pragma unroll
        for (int kk = 0; kk < 32; ++kk) {
            float a[8], b[8];
#pragma unroll
            for (int i = 0; i < 8; ++i) a[i] = As[kk][ty * 8 + i];
#pragma unroll
            for (int j = 0; j < 8; ++j) b[j] = Bs[kk][tx * 8 + j];
#pragma unroll
            for (int i = 0; i < 8; ++i)
#pragma unroll
                for (int j = 0; j < 8; ++j)
                    acc[i][j] += a[i] * b[j];
        }
        __syncthreads();
    }

#pragma unroll
    for (int i = 0; i < 8; ++i) {
        int r = row0 + ty * 8 + i;
#pragma unroll
        for (int jj = 0; jj < 2; ++jj) {
            int c = col0 + tx * 8 + jj * 4;
            float4 res = *(const float4*)&Qin[(size_t)r * ND + c];
            float4 o;
            o.x = acc[i][jj*4+0] + bias[c+0] + res.x;
            o.y = acc[i][jj*4+1] + bias[c+1] + res.y;
            o.z = acc[i][jj*4+2] + bias[c+2] + res.z;
            o.w = acc[i][jj*4+3] + bias[c+3] + res.w;
            *(float4*)&out[(size_t)r * ND + c] = o;
        }
    }
}

// ---------------------------------------------------------------------------
// In-place LayerNorm over last dim (512).
// ---------------------------------------------------------------------------
__global__ __launch_bounds__(256) void k_ln(
    float* __restrict__ out, const float* __restrict__ gamma,
    const float* __restrict__ beta)
{
    const int tid = threadIdx.x;
    float* p = out + (size_t)blockIdx.x * ND;
    float2 v = *(const float2*)&p[tid * 2];

    float s = v.x + v.y;
#pragma unroll
    for (int off = 32; off > 0; off >>= 1) s += __shfl_xor(s, off);
    __shared__ float red1[4];
    __shared__ float red2[4];
    if ((tid & 63) == 0) red1[tid >> 6] = s;
    __syncthreads();
    const float mu = (red1[0] + red1[1] + red1[2] + red1[3]) * (1.0f / ND);

    float dx = v.x - mu, dy = v.y - mu;
    float q = dx * dx + dy * dy;
#pragma unroll
    for (int off = 32; off > 0; off >>= 1) q += __shfl_xor(q, off);
    if ((tid & 63) == 0) red2[tid >> 6] = q;
    __syncthreads();
    const float var = (red2[0] + red2[1] + red2[2] + red2[3]) * (1.0f / ND);
    const float inv = rsqrtf(var + LN_EPS);

    float2 g = *(const float2*)&gamma[tid * 2];
    float2 be = *(const float2*)&beta[tid * 2];
    float2 o = { dx * inv * g.x + be.x, dy * inv * g.y + be.y };
    *(float2*)&p[tid * 2] = o;
}

// ---------------------------------------------------------------------------
extern "C" void kernel_launch(void* const* d_in, const int* in_sizes, int n_in,
                              void* d_out, int out_size, void* d_ws, size_t ws_size,
                              hipStream_t stream)
{
    const float* Q    = (const float*)d_in[0];
    const float* K    = (const float*)d_in[1];
    const float* V    = (const float*)d_in[2];
    const float* Wq   = (const float*)d_in[3];
    const float* bq   = (const float*)d_in[4];
    const float* Wk   = (const float*)d_in[5];
    const float* bk   = (const float*)d_in[6];
    const float* Wv   = (const float*)d_in[7];
    const float* bv   = (const float*)d_in[8];
    const float* Wo   = (const float*)d_in[9];
    const float* bo   = (const float*)d_in[10];
    const float* gam  = (const float*)d_in[11];
    const float* bet  = (const float*)d_in[12];

    float* out  = (float*)d_out;                       // [NB*NS*ND]
    float* attn = out + (size_t)NB * NS * ND;          // [NB*NH*NS*NS]

    const size_t QKV = (size_t)NB * NH * NS * NDK;     // 4.19M elements
    short* qh   = (short*)d_ws;
    short* ql   = qh + QKV;
    short* kh   = ql + QKV;
    short* kl   = kh + QKV;
    short* vtb  = kl + QKV;
    short* ctxb = vtb + QKV;
    float* iLrow = (float*)(ctxb + QKV);               // [32][2048]

    dim3 blk(256);

    dim3 gProj(ND / 128, (NB * NS) / 128);             // (4, 64)
    k_proj_t<0><<<gProj, blk, 0, stream>>>(Q, Wq, bq, qh, ql);
    k_proj_t<0><<<gProj, blk, 0, stream>>>(K, Wk, bk, kh, kl);
    k_proj_t<1><<<gProj, blk, 0, stream>>>(V, Wv, bv, vtb, (short*)nullptr);

    dim3 gAtt((NS / 64) * NB * NH);                    // 1024, XCD-remapped
    k_stats<<<gAtt, blk, 0, stream>>>(qh, ql, kh, kl, iLrow);
    k_pv<<<gAtt, blk, 0, stream>>>(qh, ql, kh, kl, vtb, iLrow, attn, ctxb);

    dim3 gOut(ND / 128, (NB * NS) / 128);              // (4, 64)
    k_outproj<<<gOut, blk, 0, stream>>>(ctxb, Wo, bo, Q, out);

    k_ln<<<dim3(NB * NS), blk, 0, stream>>>(out, gam, bet);
}

// Round 8
// 546.654 us; speedup vs baseline: 1.7128x; 1.7128x over previous
//
#include <hip/hip_runtime.h>

#define NB 4
#define NS 2048
#define ND 512
#define NH 8
#define NDK 64
#define LN_EPS 1e-5f
#define SCLAMP 80.0f

typedef __attribute__((ext_vector_type(8))) short short8;
typedef __attribute__((ext_vector_type(4))) float f32x4;

__device__ inline short f2bf(float x) {
    unsigned u = __builtin_bit_cast(unsigned, x);
    unsigned r = (u + 0x7FFFu + ((u >> 16) & 1u)) >> 16;
    return (short)r;
}
__device__ inline float bf2f(short h) {
    unsigned u = ((unsigned)(unsigned short)h) << 16;
    return __builtin_bit_cast(float, u);
}

// Swizzled offset (in shorts) within a [64 rows][64 cols] bf16 LDS tile.
// byte = row*128 + (b8*16 ^ ((row&7)<<4)) -> spreads the stride-128B frag
// reads across 8 distinct 16B bank groups (T2 pattern).
__device__ inline int swzS(int row, int b8) {
    return row * 64 + (((b8) * 8) ^ ((row & 7) << 3));
}

// ---------------------------------------------------------------------------
// Projection GEMM core (f32, 128x128 tile, BK=32, 8x8 micro).
// MODE 0: write bf16 hi+lo in [B,H,S,DK] layout (for Q,K -> MFMA frags)
// MODE 1: write bf16 V-transposed [B,H,DK,S] (for PV B-frags)
// ---------------------------------------------------------------------------
template<int MODE>
__global__ __launch_bounds__(256) void k_proj_t(
    const float* __restrict__ X, const float* __restrict__ W,
    const float* __restrict__ bias,
    short* __restrict__ outh, short* __restrict__ outl)
{
    __shared__ float As[32][132];
    __shared__ float Bs[32][132];
    const int tid = threadIdx.x;
    const int tx = tid & 15, ty = tid >> 4;
    const int row0 = blockIdx.y * 128;
    const int col0 = blockIdx.x * 128;
    const int sr = tid >> 3;
    const int sc = tid & 7;

    float acc[8][8] = {};

    for (int k0 = 0; k0 < ND; k0 += 32) {
#pragma unroll
        for (int i = 0; i < 4; ++i) {
            int r = sr + 32 * i;
            float4 a = *(const float4*)&X[(size_t)(row0 + r) * ND + k0 + sc * 4];
            As[sc*4+0][r]=a.x; As[sc*4+1][r]=a.y; As[sc*4+2][r]=a.z; As[sc*4+3][r]=a.w;
            float4 b = *(const float4*)&W[(size_t)(col0 + r) * ND + k0 + sc * 4];
            Bs[sc*4+0][r]=b.x; Bs[sc*4+1][r]=b.y; Bs[sc*4+2][r]=b.z; Bs[sc*4+3][r]=b.w;
        }
        __syncthreads();
#pragma unroll
        for (int kk = 0; kk < 32; ++kk) {
            float a[8], b[8];
#pragma unroll
            for (int i = 0; i < 8; ++i) a[i] = As[kk][ty * 8 + i];
#pragma unroll
            for (int j = 0; j < 8; ++j) b[j] = Bs[kk][tx * 8 + j];
#pragma unroll
            for (int i = 0; i < 8; ++i)
#pragma unroll
                for (int j = 0; j < 8; ++j)
                    acc[i][j] += a[i] * b[j];
        }
        __syncthreads();
    }

    if (MODE == 0) {
#pragma unroll
        for (int i = 0; i < 8; ++i) {
            int r = row0 + ty * 8 + i;
            int b_ = r >> 11, s_ = r & (NS - 1);
            int c0 = col0 + tx * 8;
            int h_ = c0 >> 6, dk = c0 & (NDK - 1);
            short8 hh, ll;
#pragma unroll
            for (int j = 0; j < 8; ++j) {
                float x = acc[i][j] + bias[c0 + j];
                short hb = f2bf(x);
                hh[j] = hb;
                ll[j] = f2bf(x - bf2f(hb));
            }
            size_t idx = (((size_t)b_ * NH + h_) * NS + s_) * NDK + dk;
            *(short8*)&outh[idx] = hh;
            *(short8*)&outl[idx] = ll;
        }
    } else {
        int r0 = row0 + ty * 8;
        int b_ = r0 >> 11, s0 = r0 & (NS - 1);
#pragma unroll
        for (int j = 0; j < 8; ++j) {
            int c = col0 + tx * 8 + j;
            int h_ = c >> 6, dk = c & (NDK - 1);
            short8 vv;
#pragma unroll
            for (int i = 0; i < 8; ++i) vv[i] = f2bf(acc[i][j] + bias[c]);
            *(short8*)&outh[(((size_t)b_ * NH + h_) * NDK + dk) * NS + s0] = vv;
        }
    }
}

// ---------------------------------------------------------------------------
// XCD-clustered remap: 1024 blocks = 32 bh x 32 rowtiles(64 rows).
// All row-tiles of a given bh land on the same XCD (wg % 8 == bh % 8).
// wg = (bh&7) + 8*rt + 256*(bh>>3)  <->  rt=(wg>>3)&31, bh=(wg&7)+((wg>>8)<<3)
// ---------------------------------------------------------------------------
__device__ inline void att_decode(int wg, int& bh, int& rt) {
    rt = (wg >> 3) & 31;
    bh = (wg & 7) + ((wg >> 8) << 3);
}

// ---------------------------------------------------------------------------
// Fused stats+PV: per chunk stage K hi/lo + V^T into swizzled LDS (once per
// BLOCK, 4 waves share -> 4x less L1/L2 read traffic), recompute scores,
// accumulate L (row sums of exp) AND unnormalized exp(s)@V simultaneously;
// scale by 1/L at the end. Writes iLrow + bf16 ctx. No stores in the loop.
// ---------------------------------------------------------------------------
__global__ __launch_bounds__(256) void k_pvl(
    const short* __restrict__ qh, const short* __restrict__ ql,
    const short* __restrict__ kh, const short* __restrict__ kl,
    const short* __restrict__ vtb,
    float* __restrict__ iLrow, short* __restrict__ ctxb)
{
    __shared__ short KsH[4096], KsL[4096], Vs[4096];
    __shared__ short plbf[4][16][72];   // [wave][qrow][64 keycols + 8 pad]
    const int tid = threadIdx.x;
    const int w = tid >> 6, lane = tid & 63;
    const int lr = lane & 15, lg = lane >> 4;
    int bh, rt;
    att_decode(blockIdx.x, bh, rt);
    const int row0 = rt * 64 + w * 16;
    const size_t base = (size_t)bh * NS * NDK;
    const short* vb = vtb + (size_t)bh * NDK * NS;
    const int srow0 = tid >> 3, sb8 = tid & 7;   // staging: 2 rows/thread
    const int srow1 = srow0 + 32;

    short8 ah[2], al[2];
#pragma unroll
    for (int ks = 0; ks < 2; ++ks) {
        size_t idx = base + (size_t)(row0 + lr) * NDK + ks * 32 + lg * 8;
        ah[ks] = *(const short8*)&qh[idx];
        al[ks] = *(const short8*)&ql[idx];
    }

    float lsum[4] = {0.f, 0.f, 0.f, 0.f};
    f32x4 vacc[4] = {};

    for (int c = 0; c < 32; ++c) {
        const int col0 = c * 64;
        // issue staging loads early (overlap prev chunk compute)
        short8 gh0 = *(const short8*)&kh[base + (size_t)(col0 + srow0) * NDK + sb8 * 8];
        short8 gh1 = *(const short8*)&kh[base + (size_t)(col0 + srow1) * NDK + sb8 * 8];
        short8 gl0 = *(const short8*)&kl[base + (size_t)(col0 + srow0) * NDK + sb8 * 8];
        short8 gl1 = *(const short8*)&kl[base + (size_t)(col0 + srow1) * NDK + sb8 * 8];
        short8 gv0 = *(const short8*)&vb[(size_t)srow0 * NS + col0 + sb8 * 8];
        short8 gv1 = *(const short8*)&vb[(size_t)srow1 * NS + col0 + sb8 * 8];
        __syncthreads();   // prev chunk's LDS reads complete
        *(short8*)&KsH[swzS(srow0, sb8)] = gh0;
        *(short8*)&KsH[swzS(srow1, sb8)] = gh1;
        *(short8*)&KsL[swzS(srow0, sb8)] = gl0;
        *(short8*)&KsL[swzS(srow1, sb8)] = gl1;
        *(short8*)&Vs[swzS(srow0, sb8)] = gv0;
        *(short8*)&Vs[swzS(srow1, sb8)] = gv1;
        __syncthreads();   // staged data visible

        f32x4 sa[4] = {};
#pragma unroll
        for (int cs = 0; cs < 4; ++cs)
#pragma unroll
            for (int ks = 0; ks < 2; ++ks) {
                short8 fh = *(const short8*)&KsH[swzS(cs * 16 + lr, ks * 4 + lg)];
                short8 fl = *(const short8*)&KsL[swzS(cs * 16 + lr, ks * 4 + lg)];
                sa[cs] = __builtin_amdgcn_mfma_f32_16x16x32_bf16(ah[ks], fh, sa[cs], 0, 0, 0);
                sa[cs] = __builtin_amdgcn_mfma_f32_16x16x32_bf16(ah[ks], fl, sa[cs], 0, 0, 0);
                sa[cs] = __builtin_amdgcn_mfma_f32_16x16x32_bf16(al[ks], fh, sa[cs], 0, 0, 0);
            }

        // unnormalized e = exp(s); accumulate row sums; bf16 transpose via LDS
#pragma unroll
        for (int cs = 0; cs < 4; ++cs)
#pragma unroll
            for (int r = 0; r < 4; ++r) {
                float e = __expf(fminf(sa[cs][r], SCLAMP));
                lsum[r] += e;
                plbf[w][lg * 4 + r][cs * 16 + lr] = f2bf(e);
            }
#pragma unroll
        for (int k2 = 0; k2 < 2; ++k2) {
            short8 pa = *(const short8*)&plbf[w][lr][k2 * 32 + lg * 8];
#pragma unroll
            for (int d = 0; d < 4; ++d) {
                short8 vf = *(const short8*)&Vs[swzS(d * 16 + lr, k2 * 4 + lg)];
                vacc[d] = __builtin_amdgcn_mfma_f32_16x16x32_bf16(pa, vf, vacc[d], 0, 0, 0);
            }
        }
    }

    // row-reduce L across the 16 lr lanes; all lanes get the sum
#pragma unroll
    for (int r = 0; r < 4; ++r)
#pragma unroll
        for (int off = 1; off < 16; off <<= 1)
            lsum[r] += __shfl_xor(lsum[r], off);

    float iL[4];
#pragma unroll
    for (int r = 0; r < 4; ++r) iL[r] = 1.0f / lsum[r];
    if (lr == 0) {
#pragma unroll
        for (int r = 0; r < 4; ++r)
            iLrow[(size_t)bh * NS + row0 + lg * 4 + r] = iL[r];
    }
    const int b_ = bh >> 3, h_ = bh & 7;
#pragma unroll
    for (int d = 0; d < 4; ++d)
#pragma unroll
        for (int r = 0; r < 4; ++r) {
            int row = row0 + lg * 4 + r;
            ctxb[((size_t)b_ * NS + row) * ND + h_ * NDK + d * 16 + lr] =
                f2bf(vacc[d][r] * iL[r]);
        }
}

// ---------------------------------------------------------------------------
// Attn writer: recompute scores (bitwise-identical staging + MFMA sequence),
// p = exp(min(s,80)) * iL, store f32 p to attn. LDS-staged K (block reuse).
// ---------------------------------------------------------------------------
__global__ __launch_bounds__(256) void k_attn_write(
    const short* __restrict__ qh, const short* __restrict__ ql,
    const short* __restrict__ kh, const short* __restrict__ kl,
    const float* __restrict__ iLrow, float* __restrict__ attn)
{
    __shared__ short KsH[4096], KsL[4096];
    const int tid = threadIdx.x;
    const int w = tid >> 6, lane = tid & 63;
    const int lr = lane & 15, lg = lane >> 4;
    int bh, rt;
    att_decode(blockIdx.x, bh, rt);
    const int row0 = rt * 64 + w * 16;
    const size_t base = (size_t)bh * NS * NDK;
    float* ab = attn + (size_t)bh * NS * NS;
    const int srow0 = tid >> 3, sb8 = tid & 7;
    const int srow1 = srow0 + 32;

    short8 ah[2], al[2];
#pragma unroll
    for (int ks = 0; ks < 2; ++ks) {
        size_t idx = base + (size_t)(row0 + lr) * NDK + ks * 32 + lg * 8;
        ah[ks] = *(const short8*)&qh[idx];
        al[ks] = *(const short8*)&ql[idx];
    }
    float iLr[4];
#pragma unroll
    for (int r = 0; r < 4; ++r)
        iLr[r] = iLrow[(size_t)bh * NS + row0 + lg * 4 + r];

    for (int c = 0; c < 32; ++c) {
        const int col0 = c * 64;
        short8 gh0 = *(const short8*)&kh[base + (size_t)(col0 + srow0) * NDK + sb8 * 8];
        short8 gh1 = *(const short8*)&kh[base + (size_t)(col0 + srow1) * NDK + sb8 * 8];
        short8 gl0 = *(const short8*)&kl[base + (size_t)(col0 + srow0) * NDK + sb8 * 8];
        short8 gl1 = *(const short8*)&kl[base + (size_t)(col0 + srow1) * NDK + sb8 * 8];
        __syncthreads();
        *(short8*)&KsH[swzS(srow0, sb8)] = gh0;
        *(short8*)&KsH[swzS(srow1, sb8)] = gh1;
        *(short8*)&KsL[swzS(srow0, sb8)] = gl0;
        *(short8*)&KsL[swzS(srow1, sb8)] = gl1;
        __syncthreads();

        f32x4 sa[4] = {};
#pragma unroll
        for (int cs = 0; cs < 4; ++cs)
#pragma unroll
            for (int ks = 0; ks < 2; ++ks) {
                short8 fh = *(const short8*)&KsH[swzS(cs * 16 + lr, ks * 4 + lg)];
                short8 fl = *(const short8*)&KsL[swzS(cs * 16 + lr, ks * 4 + lg)];
                sa[cs] = __builtin_amdgcn_mfma_f32_16x16x32_bf16(ah[ks], fh, sa[cs], 0, 0, 0);
                sa[cs] = __builtin_amdgcn_mfma_f32_16x16x32_bf16(ah[ks], fl, sa[cs], 0, 0, 0);
                sa[cs] = __builtin_amdgcn_mfma_f32_16x16x32_bf16(al[ks], fh, sa[cs], 0, 0, 0);
            }

#pragma unroll
        for (int cs = 0; cs < 4; ++cs)
#pragma unroll
            for (int r = 0; r < 4; ++r) {
                float p = __expf(fminf(sa[cs][r], SCLAMP)) * iLr[r];
                ab[(size_t)(row0 + lg * 4 + r) * NS + col0 + cs * 16 + lr] = p;
            }
    }
}

// ---------------------------------------------------------------------------
// out[r][c] = sum_k ctx_bf16[r][k] * Wo[c][k] + bo[c] + residual[r][c]
// ---------------------------------------------------------------------------
__global__ __launch_bounds__(256) void k_outproj(
    const short* __restrict__ Xc, const float* __restrict__ W,
    const float* __restrict__ bias, const float* __restrict__ Qin,
    float* __restrict__ out)
{
    __shared__ float As[32][132];
    __shared__ float Bs[32][132];
    const int tid = threadIdx.x;
    const int tx = tid & 15, ty = tid >> 4;
    const int row0 = blockIdx.y * 128;
    const int col0 = blockIdx.x * 128;
    const int sr = tid >> 3;
    const int sc = tid & 7;

    float acc[8][8] = {};

    for (int k0 = 0; k0 < ND; k0 += 32) {
#pragma unroll
        for (int i = 0; i < 2; ++i) {
            int ch = tid + 256 * i;
            int r = ch >> 2, kc = ch & 3;
            short8 a8 = *(const short8*)&Xc[(size_t)(row0 + r) * ND + k0 + kc * 8];
#pragma unroll
            for (int j = 0; j < 8; ++j) As[kc * 8 + j][r] = bf2f(a8[j]);
        }
#pragma unroll
        for (int i = 0; i < 4; ++i) {
            int r = sr + 32 * i;
            float4 b = *(const float4*)&W[(size_t)(col0 + r) * ND + k0 + sc * 4];
            Bs[sc*4+0][r]=b.x; Bs[sc*4+1][r]=b.y; Bs[sc*4+2][r]=b.z; Bs[sc*4+3][r]=b.w;
        }
        __syncthreads();
#pragma unroll
        for (int kk = 0; kk < 32; ++kk) {
            float a[8], b[8];
#pragma unroll
            for (int i = 0; i < 8; ++i) a[i] = As[kk][ty * 8 + i];
#pragma unroll
            for (int j = 0; j < 8; ++j) b[j] = Bs[kk][tx * 8 + j];
#pragma unroll
            for (int i = 0; i < 8; ++i)
#pragma unroll
                for (int j = 0; j < 8; ++j)
                    acc[i][j] += a[i] * b[j];
        }
        __syncthreads();
    }

#pragma unroll
    for (int i = 0; i < 8; ++i) {
        int r = row0 + ty * 8 + i;
#pragma unroll
        for (int jj = 0; jj < 2; ++jj) {
            int c = col0 + tx * 8 + jj * 4;
            float4 res = *(const float4*)&Qin[(size_t)r * ND + c];
            float4 o;
            o.x = acc[i][jj*4+0] + bias[c+0] + res.x;
            o.y = acc[i][jj*4+1] + bias[c+1] + res.y;
            o.z = acc[i][jj*4+2] + bias[c+2] + res.z;
            o.w = acc[i][jj*4+3] + bias[c+3] + res.w;
            *(float4*)&out[(size_t)r * ND + c] = o;
        }
    }
}

// ---------------------------------------------------------------------------
// In-place LayerNorm over last dim (512).
// ---------------------------------------------------------------------------
__global__ __launch_bounds__(256) void k_ln(
    float* __restrict__ out, const float* __restrict__ gamma,
    const float* __restrict__ beta)
{
    const int tid = threadIdx.x;
    float* p = out + (size_t)blockIdx.x * ND;
    float2 v = *(const float2*)&p[tid * 2];

    float s = v.x + v.y;
#pragma unroll
    for (int off = 32; off > 0; off >>= 1) s += __shfl_xor(s, off);
    __shared__ float red1[4];
    __shared__ float red2[4];
    if ((tid & 63) == 0) red1[tid >> 6] = s;
    __syncthreads();
    const float mu = (red1[0] + red1[1] + red1[2] + red1[3]) * (1.0f / ND);

    float dx = v.x - mu, dy = v.y - mu;
    float q = dx * dx + dy * dy;
#pragma unroll
    for (int off = 32; off > 0; off >>= 1) q += __shfl_xor(q, off);
    if ((tid & 63) == 0) red2[tid >> 6] = q;
    __syncthreads();
    const float var = (red2[0] + red2[1] + red2[2] + red2[3]) * (1.0f / ND);
    const float inv = rsqrtf(var + LN_EPS);

    float2 g = *(const float2*)&gamma[tid * 2];
    float2 be = *(const float2*)&beta[tid * 2];
    float2 o = { dx * inv * g.x + be.x, dy * inv * g.y + be.y };
    *(float2*)&p[tid * 2] = o;
}

// ---------------------------------------------------------------------------
extern "C" void kernel_launch(void* const* d_in, const int* in_sizes, int n_in,
                              void* d_out, int out_size, void* d_ws, size_t ws_size,
                              hipStream_t stream)
{
    const float* Q    = (const float*)d_in[0];
    const float* K    = (const float*)d_in[1];
    const float* V    = (const float*)d_in[2];
    const float* Wq   = (const float*)d_in[3];
    const float* bq   = (const float*)d_in[4];
    const float* Wk   = (const float*)d_in[5];
    const float* bk   = (const float*)d_in[6];
    const float* Wv   = (const float*)d_in[7];
    const float* bv   = (const float*)d_in[8];
    const float* Wo   = (const float*)d_in[9];
    const float* bo   = (const float*)d_in[10];
    const float* gam  = (const float*)d_in[11];
    const float* bet  = (const float*)d_in[12];

    float* out  = (float*)d_out;                       // [NB*NS*ND]
    float* attn = out + (size_t)NB * NS * ND;          // [NB*NH*NS*NS]

    const size_t QKV = (size_t)NB * NH * NS * NDK;     // 4.19M elements
    short* qh   = (short*)d_ws;
    short* ql   = qh + QKV;
    short* kh   = ql + QKV;
    short* kl   = kh + QKV;
    short* vtb  = kl + QKV;
    short* ctxb = vtb + QKV;
    float* iLrow = (float*)(ctxb + QKV);               // [32][2048]

    dim3 blk(256);

    dim3 gProj(ND / 128, (NB * NS) / 128);             // (4, 64)
    k_proj_t<0><<<gProj, blk, 0, stream>>>(Q, Wq, bq, qh, ql);
    k_proj_t<0><<<gProj, blk, 0, stream>>>(K, Wk, bk, kh, kl);
    k_proj_t<1><<<gProj, blk, 0, stream>>>(V, Wv, bv, vtb, (short*)nullptr);

    dim3 gAtt((NS / 64) * NB * NH);                    // 1024, XCD-remapped
    k_pvl<<<gAtt, blk, 0, stream>>>(qh, ql, kh, kl, vtb, iLrow, ctxb);
    k_attn_write<<<gAtt, blk, 0, stream>>>(qh, ql, kh, kl, iLrow, attn);

    dim3 gOut(ND / 128, (NB * NS) / 128);              // (4, 64)
    k_outproj<<<gOut, blk, 0, stream>>>(ctxb, Wo, bo, Q, out);

    k_ln<<<dim3(NB * NS), blk, 0, stream>>>(out, gam, bet);
}

// Round 10
// 401.824 us; speedup vs baseline: 2.3301x; 1.3604x over previous
//
#include <hip/hip_runtime.h>

#define NB 4
#define NS 2048
#define ND 512
#define NH 8
#define NDK 64
#define LN_EPS 1e-5f
#define SCLAMP 80.0f

typedef __attribute__((ext_vector_type(8))) short short8;
typedef __attribute__((ext_vector_type(4))) short s16x4;
typedef __attribute__((ext_vector_type(4))) float f32x4;

__device__ inline short f2bf(float x) {
    unsigned u = __builtin_bit_cast(unsigned, x);
    unsigned r = (u + 0x7FFFu + ((u >> 16) & 1u)) >> 16;
    return (short)r;
}
__device__ inline float bf2f(short h) {
    unsigned u = ((unsigned)(unsigned short)h) << 16;
    return __builtin_bit_cast(float, u);
}
// Dekker trunc split, packed return: low 16 = hi part, high 16 = lo part.
// hi = top-16 bits of x (exact bf16 by truncation); lo = bf16(x - hi).
__device__ inline unsigned splitT(float x) {
    unsigned u = __builtin_bit_cast(unsigned, x);
    unsigned h = u >> 16;
    float r = x - bf2f((short)h);
    unsigned l = __builtin_bit_cast(unsigned, r) >> 16;
    return (h & 0xFFFFu) | (l << 16);
}

// Swizzled offset (in shorts) within a [rows][64 cols] bf16 LDS tile.
// byte = row*128 + (b8*16 ^ ((row&7)<<4)) : stride-128B frag reads spread
// across 8 bank groups (T2). b8 = 16B granule index (0..7).
__device__ inline int swzS(int row, int b8) {
    return row * 64 + (((b8) * 8) ^ ((row & 7) << 3));
}
// same, addressed by 8B (4-short) granule g4 (0..15)
__device__ inline int swz4(int row, int g4) {
    return row * 64 + ((((g4 >> 1)) * 8) ^ ((row & 7) << 3)) + (g4 & 1) * 4;
}

// ---------------------------------------------------------------------------
// Projection via split-bf16 MFMA: P = X @ W^T + b.
// On-the-fly Dekker split of X and W; W-tile (128 cols x 64 k) staged hi/lo
// in swizzled LDS; A-frags read per-lane from global (L2), reg-prefetched.
// Tile: 64 rows (wave=16 rows) x 128 cols, K-chunks of 64.
// MODE 0: bf16 hi+lo out in [B,H,S,DK]. MODE 1: bf16 V^T out [B,H,DK,S].
// ---------------------------------------------------------------------------
template<int MODE>
__global__ __launch_bounds__(256) void k_projm(
    const float* __restrict__ X, const float* __restrict__ W,
    const float* __restrict__ bias,
    short* __restrict__ outh, short* __restrict__ outl)
{
    __shared__ short WsH[8192], WsL[8192];   // [128 rows][64 k] swizzled
    const int tid = threadIdx.x;
    const int w = tid >> 6, lane = tid & 63;
    const int lr = lane & 15, lg = lane >> 4;
    const int row0 = blockIdx.y * 64;
    const int col0 = blockIdx.x * 128;
    const int xrow = row0 + w * 16 + lr;

    f32x4 acc[8] = {};

    // ---- preload chunk 0 into regs ----
    float4 wb[8], ab[4];
#pragma unroll
    for (int i = 0; i < 8; ++i) {
        int idx = tid + 256 * i, wrow = idx >> 4, g4 = idx & 15;
        wb[i] = *(const float4*)&W[(size_t)(col0 + wrow) * ND + g4 * 4];
    }
#pragma unroll
    for (int ks = 0; ks < 2; ++ks) {
        ab[2*ks+0] = *(const float4*)&X[(size_t)xrow * ND + ks * 32 + lg * 8];
        ab[2*ks+1] = *(const float4*)&X[(size_t)xrow * ND + ks * 32 + lg * 8 + 4];
    }

    for (int kc = 0; kc < 8; ++kc) {
        __syncthreads();   // prev chunk's LDS reads done
        // ---- convert + stage W tile (hi/lo) ----
#pragma unroll
        for (int i = 0; i < 8; ++i) {
            int idx = tid + 256 * i, wrow = idx >> 4, g4 = idx & 15;
            s16x4 hv, lv;
            unsigned p0 = splitT(wb[i].x), p1 = splitT(wb[i].y);
            unsigned p2 = splitT(wb[i].z), p3 = splitT(wb[i].w);
            hv[0] = (short)p0; lv[0] = (short)(p0 >> 16);
            hv[1] = (short)p1; lv[1] = (short)(p1 >> 16);
            hv[2] = (short)p2; lv[2] = (short)(p2 >> 16);
            hv[3] = (short)p3; lv[3] = (short)(p3 >> 16);
            int off = swz4(wrow, g4);
            *(s16x4*)&WsH[off] = hv;
            *(s16x4*)&WsL[off] = lv;
        }
        __syncthreads();

        // ---- convert current A frags ----
        short8 ah[2], al[2];
#pragma unroll
        for (int ks = 0; ks < 2; ++ks) {
#pragma unroll
            for (int j = 0; j < 4; ++j) {
                unsigned p = splitT(ab[2*ks][j]);
                ah[ks][j] = (short)p; al[ks][j] = (short)(p >> 16);
            }
#pragma unroll
            for (int j = 0; j < 4; ++j) {
                unsigned p = splitT(ab[2*ks+1][j]);
                ah[ks][4+j] = (short)p; al[ks][4+j] = (short)(p >> 16);
            }
        }

        // ---- prefetch next chunk (hides under MFMA below) ----
        if (kc < 7) {
            const int kn = (kc + 1) * 64;
#pragma unroll
            for (int i = 0; i < 8; ++i) {
                int idx = tid + 256 * i, wrow = idx >> 4, g4 = idx & 15;
                wb[i] = *(const float4*)&W[(size_t)(col0 + wrow) * ND + kn + g4 * 4];
            }
#pragma unroll
            for (int ks = 0; ks < 2; ++ks) {
                ab[2*ks+0] = *(const float4*)&X[(size_t)xrow * ND + kn + ks * 32 + lg * 8];
                ab[2*ks+1] = *(const float4*)&X[(size_t)xrow * ND + kn + ks * 32 + lg * 8 + 4];
            }
        }

        // ---- MFMA: 8 col-blocks x 2 ks x 3 products ----
#pragma unroll
        for (int cs = 0; cs < 8; ++cs)
#pragma unroll
            for (int ks = 0; ks < 2; ++ks) {
                short8 fh = *(const short8*)&WsH[swzS(cs * 16 + lr, ks * 4 + lg)];
                short8 fl = *(const short8*)&WsL[swzS(cs * 16 + lr, ks * 4 + lg)];
                acc[cs] = __builtin_amdgcn_mfma_f32_16x16x32_bf16(ah[ks], fh, acc[cs], 0, 0, 0);
                acc[cs] = __builtin_amdgcn_mfma_f32_16x16x32_bf16(ah[ks], fl, acc[cs], 0, 0, 0);
                acc[cs] = __builtin_amdgcn_mfma_f32_16x16x32_bf16(al[ks], fh, acc[cs], 0, 0, 0);
            }
    }

    // ---- epilogue: D row = row0+w*16+lg*4+r, col = col0+cs*16+lr ----
#pragma unroll
    for (int cs = 0; cs < 8; ++cs) {
        int c = col0 + cs * 16 + lr;
        int h_ = c >> 6, dk = c & (NDK - 1);
        float bv = bias[c];
#pragma unroll
        for (int r = 0; r < 4; ++r) {
            int gr = row0 + w * 16 + lg * 4 + r;
            int b_ = gr >> 11, s_ = gr & (NS - 1);
            float x = acc[cs][r] + bv;
            if (MODE == 0) {
                size_t idx = (((size_t)b_ * NH + h_) * NS + s_) * NDK + dk;
                short hb = f2bf(x);
                outh[idx] = hb;
                outl[idx] = f2bf(x - bf2f(hb));
            } else {
                size_t idx = (((size_t)b_ * NH + h_) * NDK + dk) * NS + s_;
                outh[idx] = f2bf(x);
            }
        }
    }
}

// ---------------------------------------------------------------------------
// XCD-clustered remap: 1024 blocks = 32 bh x 32 rowtiles(64 rows).
// All row-tiles of a given bh land on the same XCD (wg % 8 == bh % 8).
// ---------------------------------------------------------------------------
__device__ inline void att_decode(int wg, int& bh, int& rt) {
    rt = (wg >> 3) & 31;
    bh = (wg & 7) + ((wg >> 8) << 3);
}

// ---------------------------------------------------------------------------
// Fused stats+PV with register-prefetch pipeline: stage K hi/lo + V^T into
// swizzled LDS (block-shared), issue chunk c+1 loads BEFORE compute of c
// (T14). Accumulates L and unnormalized exp(s)@V; scales by 1/L at the end.
// ---------------------------------------------------------------------------
__global__ __launch_bounds__(256) void k_pvl(
    const short* __restrict__ qh, const short* __restrict__ ql,
    const short* __restrict__ kh, const short* __restrict__ kl,
    const short* __restrict__ vtb,
    float* __restrict__ iLrow, short* __restrict__ ctxb)
{
    __shared__ short KsH[4096], KsL[4096], Vs[4096];
    __shared__ short plbf[4][16][72];
    const int tid = threadIdx.x;
    const int w = tid >> 6, lane = tid & 63;
    const int lr = lane & 15, lg = lane >> 4;
    int bh, rt;
    att_decode(blockIdx.x, bh, rt);
    const int row0 = rt * 64 + w * 16;
    const size_t base = (size_t)bh * NS * NDK;
    const short* vb = vtb + (size_t)bh * NDK * NS;
    const int srow0 = tid >> 3, sb8 = tid & 7;
    const int srow1 = srow0 + 32;

    short8 ah[2], al[2];
#pragma unroll
    for (int ks = 0; ks < 2; ++ks) {
        size_t idx = base + (size_t)(row0 + lr) * NDK + ks * 32 + lg * 8;
        ah[ks] = *(const short8*)&qh[idx];
        al[ks] = *(const short8*)&ql[idx];
    }

    float lsum[4] = {0.f, 0.f, 0.f, 0.f};
    f32x4 vacc[4] = {};

    // preload chunk 0
    short8 nh0, nh1, nl0, nl1, nv0, nv1;
    {
        nh0 = *(const short8*)&kh[base + (size_t)(srow0) * NDK + sb8 * 8];
        nh1 = *(const short8*)&kh[base + (size_t)(srow1) * NDK + sb8 * 8];
        nl0 = *(const short8*)&kl[base + (size_t)(srow0) * NDK + sb8 * 8];
        nl1 = *(const short8*)&kl[base + (size_t)(srow1) * NDK + sb8 * 8];
        nv0 = *(const short8*)&vb[(size_t)srow0 * NS + sb8 * 8];
        nv1 = *(const short8*)&vb[(size_t)srow1 * NS + sb8 * 8];
    }

    for (int c = 0; c < 32; ++c) {
        short8 ch0 = nh0, ch1 = nh1, cl0 = nl0, cl1 = nl1, cv0 = nv0, cv1 = nv1;
        __syncthreads();   // prev chunk's LDS reads complete
        *(short8*)&KsH[swzS(srow0, sb8)] = ch0;
        *(short8*)&KsH[swzS(srow1, sb8)] = ch1;
        *(short8*)&KsL[swzS(srow0, sb8)] = cl0;
        *(short8*)&KsL[swzS(srow1, sb8)] = cl1;
        *(short8*)&Vs[swzS(srow0, sb8)] = cv0;
        *(short8*)&Vs[swzS(srow1, sb8)] = cv1;
        __syncthreads();   // staged data visible

        // issue next chunk's loads now — latency hides under compute below
        if (c < 31) {
            const int coln = (c + 1) * 64;
            nh0 = *(const short8*)&kh[base + (size_t)(coln + srow0) * NDK + sb8 * 8];
            nh1 = *(const short8*)&kh[base + (size_t)(coln + srow1) * NDK + sb8 * 8];
            nl0 = *(const short8*)&kl[base + (size_t)(coln + srow0) * NDK + sb8 * 8];
            nl1 = *(const short8*)&kl[base + (size_t)(coln + srow1) * NDK + sb8 * 8];
            nv0 = *(const short8*)&vb[(size_t)srow0 * NS + coln + sb8 * 8];
            nv1 = *(const short8*)&vb[(size_t)srow1 * NS + coln + sb8 * 8];
        }

        f32x4 sa[4] = {};
#pragma unroll
        for (int cs = 0; cs < 4; ++cs)
#pragma unroll
            for (int ks = 0; ks < 2; ++ks) {
                short8 fh = *(const short8*)&KsH[swzS(cs * 16 + lr, ks * 4 + lg)];
                short8 fl = *(const short8*)&KsL[swzS(cs * 16 + lr, ks * 4 + lg)];
                sa[cs] = __builtin_amdgcn_mfma_f32_16x16x32_bf16(ah[ks], fh, sa[cs], 0, 0, 0);
                sa[cs] = __builtin_amdgcn_mfma_f32_16x16x32_bf16(ah[ks], fl, sa[cs], 0, 0, 0);
                sa[cs] = __builtin_amdgcn_mfma_f32_16x16x32_bf16(al[ks], fh, sa[cs], 0, 0, 0);
            }

#pragma unroll
        for (int cs = 0; cs < 4; ++cs)
#pragma unroll
            for (int r = 0; r < 4; ++r) {
                float e = __expf(fminf(sa[cs][r], SCLAMP));
                lsum[r] += e;
                plbf[w][lg * 4 + r][cs * 16 + lr] = f2bf(e);
            }
#pragma unroll
        for (int k2 = 0; k2 < 2; ++k2) {
            short8 pa = *(const short8*)&plbf[w][lr][k2 * 32 + lg * 8];
#pragma unroll
            for (int d = 0; d < 4; ++d) {
                short8 vf = *(const short8*)&Vs[swzS(d * 16 + lr, k2 * 4 + lg)];
                vacc[d] = __builtin_amdgcn_mfma_f32_16x16x32_bf16(pa, vf, vacc[d], 0, 0, 0);
            }
        }
    }

#pragma unroll
    for (int r = 0; r < 4; ++r)
#pragma unroll
        for (int off = 1; off < 16; off <<= 1)
            lsum[r] += __shfl_xor(lsum[r], off);

    float iL[4];
#pragma unroll
    for (int r = 0; r < 4; ++r) iL[r] = 1.0f / lsum[r];
    if (lr == 0) {
#pragma unroll
        for (int r = 0; r < 4; ++r)
            iLrow[(size_t)bh * NS + row0 + lg * 4 + r] = iL[r];
    }
    const int b_ = bh >> 3, h_ = bh & 7;
#pragma unroll
    for (int d = 0; d < 4; ++d)
#pragma unroll
        for (int r = 0; r < 4; ++r) {
            int row = row0 + lg * 4 + r;
            ctxb[((size_t)b_ * NS + row) * ND + h_ * NDK + d * 16 + lr] =
                f2bf(vacc[d][r] * iL[r]);
        }
}

// ---------------------------------------------------------------------------
// Attn writer: recompute scores (bitwise-identical staging + MFMA sequence),
// p = exp(min(s,80)) * iL, store f32 p. Same register-prefetch pipeline.
// ---------------------------------------------------------------------------
__global__ __launch_bounds__(256) void k_attn_write(
    const short* __restrict__ qh, const short* __restrict__ ql,
    const short* __restrict__ kh, const short* __restrict__ kl,
    const float* __restrict__ iLrow, float* __restrict__ attn)
{
    __shared__ short KsH[4096], KsL[4096];
    const int tid = threadIdx.x;
    const int w = tid >> 6, lane = tid & 63;
    const int lr = lane & 15, lg = lane >> 4;
    int bh, rt;
    att_decode(blockIdx.x, bh, rt);
    const int row0 = rt * 64 + w * 16;
    const size_t base = (size_t)bh * NS * NDK;
    float* ab = attn + (size_t)bh * NS * NS;
    const int srow0 = tid >> 3, sb8 = tid & 7;
    const int srow1 = srow0 + 32;

    short8 ah[2], al[2];
#pragma unroll
    for (int ks = 0; ks < 2; ++ks) {
        size_t idx = base + (size_t)(row0 + lr) * NDK + ks * 32 + lg * 8;
        ah[ks] = *(const short8*)&qh[idx];
        al[ks] = *(const short8*)&ql[idx];
    }
    float iLr[4];
#pragma unroll
    for (int r = 0; r < 4; ++r)
        iLr[r] = iLrow[(size_t)bh * NS + row0 + lg * 4 + r];

    short8 nh0, nh1, nl0, nl1;
    {
        nh0 = *(const short8*)&kh[base + (size_t)(srow0) * NDK + sb8 * 8];
        nh1 = *(const short8*)&kh[base + (size_t)(srow1) * NDK + sb8 * 8];
        nl0 = *(const short8*)&kl[base + (size_t)(srow0) * NDK + sb8 * 8];
        nl1 = *(const short8*)&kl[base + (size_t)(srow1) * NDK + sb8 * 8];
    }

    for (int c = 0; c < 32; ++c) {
        short8 ch0 = nh0, ch1 = nh1, cl0 = nl0, cl1 = nl1;
        __syncthreads();
        *(short8*)&KsH[swzS(srow0, sb8)] = ch0;
        *(short8*)&KsH[swzS(srow1, sb8)] = ch1;
        *(short8*)&KsL[swzS(srow0, sb8)] = cl0;
        *(short8*)&KsL[swzS(srow1, sb8)] = cl1;
        __syncthreads();

        if (c < 31) {
            const int coln = (c + 1) * 64;
            nh0 = *(const short8*)&kh[base + (size_t)(coln + srow0) * NDK + sb8 * 8];
            nh1 = *(const short8*)&kh[base + (size_t)(coln + srow1) * NDK + sb8 * 8];
            nl0 = *(const short8*)&kl[base + (size_t)(coln + srow0) * NDK + sb8 * 8];
            nl1 = *(const short8*)&kl[base + (size_t)(coln + srow1) * NDK + sb8 * 8];
        }

        const int col0 = c * 64;
        f32x4 sa[4] = {};
#pragma unroll
        for (int cs = 0; cs < 4; ++cs)
#pragma unroll
            for (int ks = 0; ks < 2; ++ks) {
                short8 fh = *(const short8*)&KsH[swzS(cs * 16 + lr, ks * 4 + lg)];
                short8 fl = *(const short8*)&KsL[swzS(cs * 16 + lr, ks * 4 + lg)];
                sa[cs] = __builtin_amdgcn_mfma_f32_16x16x32_bf16(ah[ks], fh, sa[cs], 0, 0, 0);
                sa[cs] = __builtin_amdgcn_mfma_f32_16x16x32_bf16(ah[ks], fl, sa[cs], 0, 0, 0);
                sa[cs] = __builtin_amdgcn_mfma_f32_16x16x32_bf16(al[ks], fh, sa[cs], 0, 0, 0);
            }

#pragma unroll
        for (int cs = 0; cs < 4; ++cs)
#pragma unroll
            for (int r = 0; r < 4; ++r) {
                float p = __expf(fminf(sa[cs][r], SCLAMP)) * iLr[r];
                ab[(size_t)(row0 + lg * 4 + r) * NS + col0 + cs * 16 + lr] = p;
            }
    }
}

// ---------------------------------------------------------------------------
// out[r][c] = sum_k ctx_bf16[r][k] * Wo[c][k] + bo[c] + residual[r][c]
// ---------------------------------------------------------------------------
__global__ __launch_bounds__(256) void k_outproj(
    const short* __restrict__ Xc, const float* __restrict__ W,
    const float* __restrict__ bias, const float* __restrict__ Qin,
    float* __restrict__ out)
{
    __shared__ float As[32][132];
    __shared__ float Bs[32][132];
    const int tid = threadIdx.x;
    const int tx = tid & 15, ty = tid >> 4;
    const int row0 = blockIdx.y * 128;
    const int col0 = blockIdx.x * 128;
    const int sr = tid >> 3;
    const int sc = tid & 7;

    float acc[8][8] = {};

    for (int k0 = 0; k0 < ND; k0 += 32) {
#pragma unroll
        for (int i = 0; i < 2; ++i) {
            int ch = tid + 256 * i;
            int r = ch >> 2, kc = ch & 3;
            short8 a8 = *(const short8*)&Xc[(size_t)(row0 + r) * ND + k0 + kc * 8];
#pragma unroll
            for (int j = 0; j < 8; ++j) As[kc * 8 + j][r] = bf2f(a8[j]);
        }
#pragma unroll
        for (int i = 0; i < 4; ++i) {
            int r = sr + 32 * i;
            float4 b = *(const float4*)&W[(size_t)(col0 + r) * ND + k0 + sc * 4];
            Bs[sc*4+0][r]=b.x; Bs[sc*4+1][r]=b.y; Bs[sc*4+2][r]=b.z; Bs[sc*4+3][r]=b.w;
        }
        __syncthreads();
#pragma unroll
        for (int kk = 0; kk < 32; ++kk) {
            float a[8], b[8];
#pragma unroll
            for (int i = 0; i < 8; ++i) a[i] = As[kk][ty * 8 + i];
#pragma unroll
            for (int j = 0; j < 8; ++j) b[j] = Bs[kk][tx * 8 + j];
#pragma unroll
            for (int i = 0; i < 8; ++i)
#pragma unroll
                for (int j = 0; j < 8; ++j)
                    acc[i][j] += a[i] * b[j];
        }
        __syncthreads();
    }

#pragma unroll
    for (int i = 0; i < 8; ++i) {
        int r = row0 + ty * 8 + i;
#pragma unroll
        for (int jj = 0; jj < 2; ++jj) {
            int c = col0 + tx * 8 + jj * 4;
            float4 res = *(const float4*)&Qin[(size_t)r * ND + c];
            float4 o;
            o.x = acc[i][jj*4+0] + bias[c+0] + res.x;
            o.y = acc[i][jj*4+1] + bias[c+1] + res.y;
            o.z = acc[i][jj*4+2] + bias[c+2] + res.z;
            o.w = acc[i][jj*4+3] + bias[c+3] + res.w;
            *(float4*)&out[(size_t)r * ND + c] = o;
        }
    }
}

// ---------------------------------------------------------------------------
// In-place LayerNorm over last dim (512).
// ---------------------------------------------------------------------------
__global__ __launch_bounds__(256) void k_ln(
    float* __restrict__ out, const float* __restrict__ gamma,
    const float* __restrict__ beta)
{
    const int tid = threadIdx.x;
    float* p = out + (size_t)blockIdx.x * ND;
    float2 v = *(const float2*)&p[tid * 2];

    float s = v.x + v.y;
#pragma unroll
    for (int off = 32; off > 0; off >>= 1) s += __shfl_xor(s, off);
    __shared__ float red1[4];
    __shared__ float red2[4];
    if ((tid & 63) == 0) red1[tid >> 6] = s;
    __syncthreads();
    const float mu = (red1[0] + red1[1] + red1[2] + red1[3]) * (1.0f / ND);

    float dx = v.x - mu, dy = v.y - mu;
    float q = dx * dx + dy * dy;
#pragma unroll
    for (int off = 32; off > 0; off >>= 1) q += __shfl_xor(q, off);
    if ((tid & 63) == 0) red2[tid >> 6] = q;
    __syncthreads();
    const float var = (red2[0] + red2[1] + red2[2] + red2[3]) * (1.0f / ND);
    const float inv = rsqrtf(var + LN_EPS);

    float2 g = *(const float2*)&gamma[tid * 2];
    float2 be = *(const float2*)&beta[tid * 2];
    float2 o = { dx * inv * g.x + be.x, dy * inv * g.y + be.y };
    *(float2*)&p[tid * 2] = o;
}

// ---------------------------------------------------------------------------
extern "C" void kernel_launch(void* const* d_in, const int* in_sizes, int n_in,
                              void* d_out, int out_size, void* d_ws, size_t ws_size,
                              hipStream_t stream)
{
    const float* Q    = (const float*)d_in[0];
    const float* K    = (const float*)d_in[1];
    const float* V    = (const float*)d_in[2];
    const float* Wq   = (const float*)d_in[3];
    const float* bq   = (const float*)d_in[4];
    const float* Wk   = (const float*)d_in[5];
    const float* bk   = (const float*)d_in[6];
    const float* Wv   = (const float*)d_in[7];
    const float* bv   = (const float*)d_in[8];
    const float* Wo   = (const float*)d_in[9];
    const float* bo   = (const float*)d_in[10];
    const float* gam  = (const float*)d_in[11];
    const float* bet  = (const float*)d_in[12];

    float* out  = (float*)d_out;                       // [NB*NS*ND]
    float* attn = out + (size_t)NB * NS * ND;          // [NB*NH*NS*NS]

    const size_t QKV = (size_t)NB * NH * NS * NDK;     // 4.19M elements
    short* qh   = (short*)d_ws;
    short* ql   = qh + QKV;
    short* kh   = ql + QKV;
    short* kl   = kh + QKV;
    short* vtb  = kl + QKV;
    short* ctxb = vtb + QKV;
    float* iLrow = (float*)(ctxb + QKV);               // [32][2048]

    dim3 blk(256);

    dim3 gP(ND / 128, (NB * NS) / 64);                 // (4, 128)
    k_projm<0><<<gP, blk, 0, stream>>>(Q, Wq, bq, qh, ql);
    k_projm<0><<<gP, blk, 0, stream>>>(K, Wk, bk, kh, kl);
    k_projm<1><<<gP, blk, 0, stream>>>(V, Wv, bv, vtb, (short*)nullptr);

    dim3 gAtt((NS / 64) * NB * NH);                    // 1024, XCD-remapped
    k_pvl<<<gAtt, blk, 0, stream>>>(qh, ql, kh, kl, vtb, iLrow, ctxb);
    k_attn_write<<<gAtt, blk, 0, stream>>>(qh, ql, kh, kl, iLrow, attn);

    dim3 gOut(ND / 128, (NB * NS) / 128);              // (4, 64)
    k_outproj<<<gOut, blk, 0, stream>>>(ctxb, Wo, bo, Q, out);

    k_ln<<<dim3(NB * NS), blk, 0, stream>>>(out, gam, bet);
}

// Round 11
// 352.236 us; speedup vs baseline: 2.6582x; 1.1408x over previous
//
#include <hip/hip_runtime.h>

#define NB 4
#define NS 2048
#define ND 512
#define NH 8
#define NDK 64
#define LN_EPS 1e-5f
#define SCLAMP 80.0f

typedef __attribute__((ext_vector_type(8))) short short8;
typedef __attribute__((ext_vector_type(4))) short s16x4;
typedef __attribute__((ext_vector_type(4))) float f32x4;

__device__ inline short f2bf(float x) {
    unsigned u = __builtin_bit_cast(unsigned, x);
    unsigned r = (u + 0x7FFFu + ((u >> 16) & 1u)) >> 16;
    return (short)r;
}
__device__ inline float bf2f(short h) {
    unsigned u = ((unsigned)(unsigned short)h) << 16;
    return __builtin_bit_cast(float, u);
}
// Dekker trunc split, packed return: low 16 = hi part, high 16 = lo part.
__device__ inline unsigned splitT(float x) {
    unsigned u = __builtin_bit_cast(unsigned, x);
    unsigned h = u >> 16;
    float r = x - bf2f((short)h);
    unsigned l = __builtin_bit_cast(unsigned, r) >> 16;
    return (h & 0xFFFFu) | (l << 16);
}

// Swizzled offset (in shorts) within a [rows][64 cols] bf16 LDS tile.
__device__ inline int swzS(int row, int b8) {
    return row * 64 + (((b8) * 8) ^ ((row & 7) << 3));
}
// same, addressed by 8B (4-short) granule g4 (0..15)
__device__ inline int swz4(int row, int g4) {
    return row * 64 + ((((g4 >> 1)) * 8) ^ ((row & 7) << 3)) + (g4 & 1) * 4;
}

// ---------------------------------------------------------------------------
// Projection via split-bf16 MFMA: P = X @ W^T + b.  (verified round 10)
// MODE 0: bf16 hi+lo out in [B,H,S,DK]. MODE 1: bf16 V^T out [B,H,DK,S].
// ---------------------------------------------------------------------------
template<int MODE>
__global__ __launch_bounds__(256) void k_projm(
    const float* __restrict__ X, const float* __restrict__ W,
    const float* __restrict__ bias,
    short* __restrict__ outh, short* __restrict__ outl)
{
    __shared__ short WsH[8192], WsL[8192];   // [128 rows][64 k] swizzled
    const int tid = threadIdx.x;
    const int w = tid >> 6, lane = tid & 63;
    const int lr = lane & 15, lg = lane >> 4;
    const int row0 = blockIdx.y * 64;
    const int col0 = blockIdx.x * 128;
    const int xrow = row0 + w * 16 + lr;

    f32x4 acc[8] = {};

    float4 wb[8], ab[4];
#pragma unroll
    for (int i = 0; i < 8; ++i) {
        int idx = tid + 256 * i, wrow = idx >> 4, g4 = idx & 15;
        wb[i] = *(const float4*)&W[(size_t)(col0 + wrow) * ND + g4 * 4];
    }
#pragma unroll
    for (int ks = 0; ks < 2; ++ks) {
        ab[2*ks+0] = *(const float4*)&X[(size_t)xrow * ND + ks * 32 + lg * 8];
        ab[2*ks+1] = *(const float4*)&X[(size_t)xrow * ND + ks * 32 + lg * 8 + 4];
    }

    for (int kc = 0; kc < 8; ++kc) {
        __syncthreads();
#pragma unroll
        for (int i = 0; i < 8; ++i) {
            int idx = tid + 256 * i, wrow = idx >> 4, g4 = idx & 15;
            s16x4 hv, lv;
            unsigned p0 = splitT(wb[i].x), p1 = splitT(wb[i].y);
            unsigned p2 = splitT(wb[i].z), p3 = splitT(wb[i].w);
            hv[0] = (short)p0; lv[0] = (short)(p0 >> 16);
            hv[1] = (short)p1; lv[1] = (short)(p1 >> 16);
            hv[2] = (short)p2; lv[2] = (short)(p2 >> 16);
            hv[3] = (short)p3; lv[3] = (short)(p3 >> 16);
            int off = swz4(wrow, g4);
            *(s16x4*)&WsH[off] = hv;
            *(s16x4*)&WsL[off] = lv;
        }
        __syncthreads();

        short8 ah[2], al[2];
#pragma unroll
        for (int ks = 0; ks < 2; ++ks) {
#pragma unroll
            for (int j = 0; j < 4; ++j) {
                unsigned p = splitT(ab[2*ks][j]);
                ah[ks][j] = (short)p; al[ks][j] = (short)(p >> 16);
            }
#pragma unroll
            for (int j = 0; j < 4; ++j) {
                unsigned p = splitT(ab[2*ks+1][j]);
                ah[ks][4+j] = (short)p; al[ks][4+j] = (short)(p >> 16);
            }
        }

        if (kc < 7) {
            const int kn = (kc + 1) * 64;
#pragma unroll
            for (int i = 0; i < 8; ++i) {
                int idx = tid + 256 * i, wrow = idx >> 4, g4 = idx & 15;
                wb[i] = *(const float4*)&W[(size_t)(col0 + wrow) * ND + kn + g4 * 4];
            }
#pragma unroll
            for (int ks = 0; ks < 2; ++ks) {
                ab[2*ks+0] = *(const float4*)&X[(size_t)xrow * ND + kn + ks * 32 + lg * 8];
                ab[2*ks+1] = *(const float4*)&X[(size_t)xrow * ND + kn + ks * 32 + lg * 8 + 4];
            }
        }

#pragma unroll
        for (int cs = 0; cs < 8; ++cs)
#pragma unroll
            for (int ks = 0; ks < 2; ++ks) {
                short8 fh = *(const short8*)&WsH[swzS(cs * 16 + lr, ks * 4 + lg)];
                short8 fl = *(const short8*)&WsL[swzS(cs * 16 + lr, ks * 4 + lg)];
                acc[cs] = __builtin_amdgcn_mfma_f32_16x16x32_bf16(ah[ks], fh, acc[cs], 0, 0, 0);
                acc[cs] = __builtin_amdgcn_mfma_f32_16x16x32_bf16(ah[ks], fl, acc[cs], 0, 0, 0);
                acc[cs] = __builtin_amdgcn_mfma_f32_16x16x32_bf16(al[ks], fh, acc[cs], 0, 0, 0);
            }
    }

#pragma unroll
    for (int cs = 0; cs < 8; ++cs) {
        int c = col0 + cs * 16 + lr;
        int h_ = c >> 6, dk = c & (NDK - 1);
        float bv = bias[c];
#pragma unroll
        for (int r = 0; r < 4; ++r) {
            int gr = row0 + w * 16 + lg * 4 + r;
            int b_ = gr >> 11, s_ = gr & (NS - 1);
            float x = acc[cs][r] + bv;
            if (MODE == 0) {
                size_t idx = (((size_t)b_ * NH + h_) * NS + s_) * NDK + dk;
                short hb = f2bf(x);
                outh[idx] = hb;
                outl[idx] = f2bf(x - bf2f(hb));
            } else {
                size_t idx = (((size_t)b_ * NH + h_) * NDK + dk) * NS + s_;
                outh[idx] = f2bf(x);
            }
        }
    }
}

// ---------------------------------------------------------------------------
// XCD-clustered remap: 1024 blocks = 32 bh x 32 rowtiles(64 rows).
// ---------------------------------------------------------------------------
__device__ inline void att_decode(int wg, int& bh, int& rt) {
    rt = (wg >> 3) & 31;
    bh = (wg & 7) + ((wg >> 8) << 3);
}

// ---------------------------------------------------------------------------
// Fused stats+PV with register-prefetch pipeline.  (verified round 8/10)
// ---------------------------------------------------------------------------
__global__ __launch_bounds__(256) void k_pvl(
    const short* __restrict__ qh, const short* __restrict__ ql,
    const short* __restrict__ kh, const short* __restrict__ kl,
    const short* __restrict__ vtb,
    float* __restrict__ iLrow, short* __restrict__ ctxb)
{
    __shared__ short KsH[4096], KsL[4096], Vs[4096];
    __shared__ short plbf[4][16][72];
    const int tid = threadIdx.x;
    const int w = tid >> 6, lane = tid & 63;
    const int lr = lane & 15, lg = lane >> 4;
    int bh, rt;
    att_decode(blockIdx.x, bh, rt);
    const int row0 = rt * 64 + w * 16;
    const size_t base = (size_t)bh * NS * NDK;
    const short* vb = vtb + (size_t)bh * NDK * NS;
    const int srow0 = tid >> 3, sb8 = tid & 7;
    const int srow1 = srow0 + 32;

    short8 ah[2], al[2];
#pragma unroll
    for (int ks = 0; ks < 2; ++ks) {
        size_t idx = base + (size_t)(row0 + lr) * NDK + ks * 32 + lg * 8;
        ah[ks] = *(const short8*)&qh[idx];
        al[ks] = *(const short8*)&ql[idx];
    }

    float lsum[4] = {0.f, 0.f, 0.f, 0.f};
    f32x4 vacc[4] = {};

    short8 nh0, nh1, nl0, nl1, nv0, nv1;
    {
        nh0 = *(const short8*)&kh[base + (size_t)(srow0) * NDK + sb8 * 8];
        nh1 = *(const short8*)&kh[base + (size_t)(srow1) * NDK + sb8 * 8];
        nl0 = *(const short8*)&kl[base + (size_t)(srow0) * NDK + sb8 * 8];
        nl1 = *(const short8*)&kl[base + (size_t)(srow1) * NDK + sb8 * 8];
        nv0 = *(const short8*)&vb[(size_t)srow0 * NS + sb8 * 8];
        nv1 = *(const short8*)&vb[(size_t)srow1 * NS + sb8 * 8];
    }

    for (int c = 0; c < 32; ++c) {
        short8 ch0 = nh0, ch1 = nh1, cl0 = nl0, cl1 = nl1, cv0 = nv0, cv1 = nv1;
        __syncthreads();
        *(short8*)&KsH[swzS(srow0, sb8)] = ch0;
        *(short8*)&KsH[swzS(srow1, sb8)] = ch1;
        *(short8*)&KsL[swzS(srow0, sb8)] = cl0;
        *(short8*)&KsL[swzS(srow1, sb8)] = cl1;
        *(short8*)&Vs[swzS(srow0, sb8)] = cv0;
        *(short8*)&Vs[swzS(srow1, sb8)] = cv1;
        __syncthreads();

        if (c < 31) {
            const int coln = (c + 1) * 64;
            nh0 = *(const short8*)&kh[base + (size_t)(coln + srow0) * NDK + sb8 * 8];
            nh1 = *(const short8*)&kh[base + (size_t)(coln + srow1) * NDK + sb8 * 8];
            nl0 = *(const short8*)&kl[base + (size_t)(coln + srow0) * NDK + sb8 * 8];
            nl1 = *(const short8*)&kl[base + (size_t)(coln + srow1) * NDK + sb8 * 8];
            nv0 = *(const short8*)&vb[(size_t)srow0 * NS + coln + sb8 * 8];
            nv1 = *(const short8*)&vb[(size_t)srow1 * NS + coln + sb8 * 8];
        }

        f32x4 sa[4] = {};
#pragma unroll
        for (int cs = 0; cs < 4; ++cs)
#pragma unroll
            for (int ks = 0; ks < 2; ++ks) {
                short8 fh = *(const short8*)&KsH[swzS(cs * 16 + lr, ks * 4 + lg)];
                short8 fl = *(const short8*)&KsL[swzS(cs * 16 + lr, ks * 4 + lg)];
                sa[cs] = __builtin_amdgcn_mfma_f32_16x16x32_bf16(ah[ks], fh, sa[cs], 0, 0, 0);
                sa[cs] = __builtin_amdgcn_mfma_f32_16x16x32_bf16(ah[ks], fl, sa[cs], 0, 0, 0);
                sa[cs] = __builtin_amdgcn_mfma_f32_16x16x32_bf16(al[ks], fh, sa[cs], 0, 0, 0);
            }

#pragma unroll
        for (int cs = 0; cs < 4; ++cs)
#pragma unroll
            for (int r = 0; r < 4; ++r) {
                float e = __expf(fminf(sa[cs][r], SCLAMP));
                lsum[r] += e;
                plbf[w][lg * 4 + r][cs * 16 + lr] = f2bf(e);
            }
#pragma unroll
        for (int k2 = 0; k2 < 2; ++k2) {
            short8 pa = *(const short8*)&plbf[w][lr][k2 * 32 + lg * 8];
#pragma unroll
            for (int d = 0; d < 4; ++d) {
                short8 vf = *(const short8*)&Vs[swzS(d * 16 + lr, k2 * 4 + lg)];
                vacc[d] = __builtin_amdgcn_mfma_f32_16x16x32_bf16(pa, vf, vacc[d], 0, 0, 0);
            }
        }
    }

#pragma unroll
    for (int r = 0; r < 4; ++r)
#pragma unroll
        for (int off = 1; off < 16; off <<= 1)
            lsum[r] += __shfl_xor(lsum[r], off);

    float iL[4];
#pragma unroll
    for (int r = 0; r < 4; ++r) iL[r] = 1.0f / lsum[r];
    if (lr == 0) {
#pragma unroll
        for (int r = 0; r < 4; ++r)
            iLrow[(size_t)bh * NS + row0 + lg * 4 + r] = iL[r];
    }
    const int b_ = bh >> 3, h_ = bh & 7;
#pragma unroll
    for (int d = 0; d < 4; ++d)
#pragma unroll
        for (int r = 0; r < 4; ++r) {
            int row = row0 + lg * 4 + r;
            ctxb[((size_t)b_ * NS + row) * ND + h_ * NDK + d * 16 + lr] =
                f2bf(vacc[d][r] * iL[r]);
        }
}

// ---------------------------------------------------------------------------
// Attn writer: recompute scores, p = exp(min(s,80))*iL, store f32 p.
// ---------------------------------------------------------------------------
__global__ __launch_bounds__(256) void k_attn_write(
    const short* __restrict__ qh, const short* __restrict__ ql,
    const short* __restrict__ kh, const short* __restrict__ kl,
    const float* __restrict__ iLrow, float* __restrict__ attn)
{
    __shared__ short KsH[4096], KsL[4096];
    const int tid = threadIdx.x;
    const int w = tid >> 6, lane = tid & 63;
    const int lr = lane & 15, lg = lane >> 4;
    int bh, rt;
    att_decode(blockIdx.x, bh, rt);
    const int row0 = rt * 64 + w * 16;
    const size_t base = (size_t)bh * NS * NDK;
    float* ab = attn + (size_t)bh * NS * NS;
    const int srow0 = tid >> 3, sb8 = tid & 7;
    const int srow1 = srow0 + 32;

    short8 ah[2], al[2];
#pragma unroll
    for (int ks = 0; ks < 2; ++ks) {
        size_t idx = base + (size_t)(row0 + lr) * NDK + ks * 32 + lg * 8;
        ah[ks] = *(const short8*)&qh[idx];
        al[ks] = *(const short8*)&ql[idx];
    }
    float iLr[4];
#pragma unroll
    for (int r = 0; r < 4; ++r)
        iLr[r] = iLrow[(size_t)bh * NS + row0 + lg * 4 + r];

    short8 nh0, nh1, nl0, nl1;
    {
        nh0 = *(const short8*)&kh[base + (size_t)(srow0) * NDK + sb8 * 8];
        nh1 = *(const short8*)&kh[base + (size_t)(srow1) * NDK + sb8 * 8];
        nl0 = *(const short8*)&kl[base + (size_t)(srow0) * NDK + sb8 * 8];
        nl1 = *(const short8*)&kl[base + (size_t)(srow1) * NDK + sb8 * 8];
    }

    for (int c = 0; c < 32; ++c) {
        short8 ch0 = nh0, ch1 = nh1, cl0 = nl0, cl1 = nl1;
        __syncthreads();
        *(short8*)&KsH[swzS(srow0, sb8)] = ch0;
        *(short8*)&KsH[swzS(srow1, sb8)] = ch1;
        *(short8*)&KsL[swzS(srow0, sb8)] = cl0;
        *(short8*)&KsL[swzS(srow1, sb8)] = cl1;
        __syncthreads();

        if (c < 31) {
            const int coln = (c + 1) * 64;
            nh0 = *(const short8*)&kh[base + (size_t)(coln + srow0) * NDK + sb8 * 8];
            nh1 = *(const short8*)&kh[base + (size_t)(coln + srow1) * NDK + sb8 * 8];
            nl0 = *(const short8*)&kl[base + (size_t)(coln + srow0) * NDK + sb8 * 8];
            nl1 = *(const short8*)&kl[base + (size_t)(coln + srow1) * NDK + sb8 * 8];
        }

        const int col0 = c * 64;
        f32x4 sa[4] = {};
#pragma unroll
        for (int cs = 0; cs < 4; ++cs)
#pragma unroll
            for (int ks = 0; ks < 2; ++ks) {
                short8 fh = *(const short8*)&KsH[swzS(cs * 16 + lr, ks * 4 + lg)];
                short8 fl = *(const short8*)&KsL[swzS(cs * 16 + lr, ks * 4 + lg)];
                sa[cs] = __builtin_amdgcn_mfma_f32_16x16x32_bf16(ah[ks], fh, sa[cs], 0, 0, 0);
                sa[cs] = __builtin_amdgcn_mfma_f32_16x16x32_bf16(ah[ks], fl, sa[cs], 0, 0, 0);
                sa[cs] = __builtin_amdgcn_mfma_f32_16x16x32_bf16(al[ks], fh, sa[cs], 0, 0, 0);
            }

#pragma unroll
        for (int cs = 0; cs < 4; ++cs)
#pragma unroll
            for (int r = 0; r < 4; ++r) {
                float p = __expf(fminf(sa[cs][r], SCLAMP)) * iLr[r];
                ab[(size_t)(row0 + lg * 4 + r) * NS + col0 + cs * 16 + lr] = p;
            }
    }
}

// ---------------------------------------------------------------------------
// Out-projection via MFMA: out = ctx_bf16 @ Wo^T + bo + residual (f32 out).
// ctx is already bf16 -> A frags load directly (no split, 2 products with
// W hi/lo). W staged hi/lo in swizzled LDS, k_projm pipeline structure.
// ---------------------------------------------------------------------------
__global__ __launch_bounds__(256) void k_outproj_m(
    const short* __restrict__ Xc, const float* __restrict__ W,
    const float* __restrict__ bias, const float* __restrict__ Qin,
    float* __restrict__ out)
{
    __shared__ short WsH[8192], WsL[8192];   // [128 rows][64 k] swizzled
    const int tid = threadIdx.x;
    const int w = tid >> 6, lane = tid & 63;
    const int lr = lane & 15, lg = lane >> 4;
    const int row0 = blockIdx.y * 64;
    const int col0 = blockIdx.x * 128;
    const int xrow = row0 + w * 16 + lr;

    f32x4 acc[8] = {};

    float4 wb[8];
    short8 abn[2];
#pragma unroll
    for (int i = 0; i < 8; ++i) {
        int idx = tid + 256 * i, wrow = idx >> 4, g4 = idx & 15;
        wb[i] = *(const float4*)&W[(size_t)(col0 + wrow) * ND + g4 * 4];
    }
#pragma unroll
    for (int ks = 0; ks < 2; ++ks)
        abn[ks] = *(const short8*)&Xc[(size_t)xrow * ND + ks * 32 + lg * 8];

    for (int kc = 0; kc < 8; ++kc) {
        __syncthreads();
#pragma unroll
        for (int i = 0; i < 8; ++i) {
            int idx = tid + 256 * i, wrow = idx >> 4, g4 = idx & 15;
            s16x4 hv, lv;
            unsigned p0 = splitT(wb[i].x), p1 = splitT(wb[i].y);
            unsigned p2 = splitT(wb[i].z), p3 = splitT(wb[i].w);
            hv[0] = (short)p0; lv[0] = (short)(p0 >> 16);
            hv[1] = (short)p1; lv[1] = (short)(p1 >> 16);
            hv[2] = (short)p2; lv[2] = (short)(p2 >> 16);
            hv[3] = (short)p3; lv[3] = (short)(p3 >> 16);
            int off = swz4(wrow, g4);
            *(s16x4*)&WsH[off] = hv;
            *(s16x4*)&WsL[off] = lv;
        }
        __syncthreads();

        short8 ah[2] = { abn[0], abn[1] };

        if (kc < 7) {
            const int kn = (kc + 1) * 64;
#pragma unroll
            for (int i = 0; i < 8; ++i) {
                int idx = tid + 256 * i, wrow = idx >> 4, g4 = idx & 15;
                wb[i] = *(const float4*)&W[(size_t)(col0 + wrow) * ND + kn + g4 * 4];
            }
#pragma unroll
            for (int ks = 0; ks < 2; ++ks)
                abn[ks] = *(const short8*)&Xc[(size_t)xrow * ND + kn + ks * 32 + lg * 8];
        }

#pragma unroll
        for (int cs = 0; cs < 8; ++cs)
#pragma unroll
            for (int ks = 0; ks < 2; ++ks) {
                short8 fh = *(const short8*)&WsH[swzS(cs * 16 + lr, ks * 4 + lg)];
                short8 fl = *(const short8*)&WsL[swzS(cs * 16 + lr, ks * 4 + lg)];
                acc[cs] = __builtin_amdgcn_mfma_f32_16x16x32_bf16(ah[ks], fh, acc[cs], 0, 0, 0);
                acc[cs] = __builtin_amdgcn_mfma_f32_16x16x32_bf16(ah[ks], fl, acc[cs], 0, 0, 0);
            }
    }

#pragma unroll
    for (int cs = 0; cs < 8; ++cs) {
        int c = col0 + cs * 16 + lr;
        float bv = bias[c];
#pragma unroll
        for (int r = 0; r < 4; ++r) {
            int gr = row0 + w * 16 + lg * 4 + r;
            float res = Qin[(size_t)gr * ND + c];
            out[(size_t)gr * ND + c] = acc[cs][r] + bv + res;
        }
    }
}

// ---------------------------------------------------------------------------
// In-place LayerNorm over last dim (512).
// ---------------------------------------------------------------------------
__global__ __launch_bounds__(256) void k_ln(
    float* __restrict__ out, const float* __restrict__ gamma,
    const float* __restrict__ beta)
{
    const int tid = threadIdx.x;
    float* p = out + (size_t)blockIdx.x * ND;
    float2 v = *(const float2*)&p[tid * 2];

    float s = v.x + v.y;
#pragma unroll
    for (int off = 32; off > 0; off >>= 1) s += __shfl_xor(s, off);
    __shared__ float red1[4];
    __shared__ float red2[4];
    if ((tid & 63) == 0) red1[tid >> 6] = s;
    __syncthreads();
    const float mu = (red1[0] + red1[1] + red1[2] + red1[3]) * (1.0f / ND);

    float dx = v.x - mu, dy = v.y - mu;
    float q = dx * dx + dy * dy;
#pragma unroll
    for (int off = 32; off > 0; off >>= 1) q += __shfl_xor(q, off);
    if ((tid & 63) == 0) red2[tid >> 6] = q;
    __syncthreads();
    const float var = (red2[0] + red2[1] + red2[2] + red2[3]) * (1.0f / ND);
    const float inv = rsqrtf(var + LN_EPS);

    float2 g = *(const float2*)&gamma[tid * 2];
    float2 be = *(const float2*)&beta[tid * 2];
    float2 o = { dx * inv * g.x + be.x, dy * inv * g.y + be.y };
    *(float2*)&p[tid * 2] = o;
}

// ---------------------------------------------------------------------------
extern "C" void kernel_launch(void* const* d_in, const int* in_sizes, int n_in,
                              void* d_out, int out_size, void* d_ws, size_t ws_size,
                              hipStream_t stream)
{
    const float* Q    = (const float*)d_in[0];
    const float* K    = (const float*)d_in[1];
    const float* V    = (const float*)d_in[2];
    const float* Wq   = (const float*)d_in[3];
    const float* bq   = (const float*)d_in[4];
    const float* Wk   = (const float*)d_in[5];
    const float* bk   = (const float*)d_in[6];
    const float* Wv   = (const float*)d_in[7];
    const float* bv   = (const float*)d_in[8];
    const float* Wo   = (const float*)d_in[9];
    const float* bo   = (const float*)d_in[10];
    const float* gam  = (const float*)d_in[11];
    const float* bet  = (const float*)d_in[12];

    float* out  = (float*)d_out;                       // [NB*NS*ND]
    float* attn = out + (size_t)NB * NS * ND;          // [NB*NH*NS*NS]

    const size_t QKV = (size_t)NB * NH * NS * NDK;     // 4.19M elements
    short* qh   = (short*)d_ws;
    short* ql   = qh + QKV;
    short* kh   = ql + QKV;
    short* kl   = kh + QKV;
    short* vtb  = kl + QKV;
    short* ctxb = vtb + QKV;
    float* iLrow = (float*)(ctxb + QKV);               // [32][2048]

    dim3 blk(256);

    dim3 gP(ND / 128, (NB * NS) / 64);                 // (4, 128)
    k_projm<0><<<gP, blk, 0, stream>>>(Q, Wq, bq, qh, ql);
    k_projm<0><<<gP, blk, 0, stream>>>(K, Wk, bk, kh, kl);
    k_projm<1><<<gP, blk, 0, stream>>>(V, Wv, bv, vtb, (short*)nullptr);

    dim3 gAtt((NS / 64) * NB * NH);                    // 1024, XCD-remapped
    k_pvl<<<gAtt, blk, 0, stream>>>(qh, ql, kh, kl, vtb, iLrow, ctxb);
    k_attn_write<<<gAtt, blk, 0, stream>>>(qh, ql, kh, kl, iLrow, attn);

    dim3 gO(ND / 128, (NB * NS) / 64);                 // (4, 128)
    k_outproj_m<<<gO, blk, 0, stream>>>(ctxb, Wo, bo, Q, out);

    k_ln<<<dim3(NB * NS), blk, 0, stream>>>(out, gam, bet);
}

// Round 12
// 332.029 us; speedup vs baseline: 2.8199x; 1.0609x over previous
//
#include <hip/hip_runtime.h>

#define NB 4
#define NS 2048
#define ND 512
#define NH 8
#define NDK 64
#define LN_EPS 1e-5f
#define SCLAMP 80.0f

typedef __attribute__((ext_vector_type(8))) short short8;
typedef __attribute__((ext_vector_type(4))) short s16x4;
typedef __attribute__((ext_vector_type(4))) float f32x4;

__device__ inline short f2bf(float x) {
    unsigned u = __builtin_bit_cast(unsigned, x);
    unsigned r = (u + 0x7FFFu + ((u >> 16) & 1u)) >> 16;
    return (short)r;
}
__device__ inline float bf2f(short h) {
    unsigned u = ((unsigned)(unsigned short)h) << 16;
    return __builtin_bit_cast(float, u);
}
// Dekker trunc split, packed return: low 16 = hi part, high 16 = lo part.
__device__ inline unsigned splitT(float x) {
    unsigned u = __builtin_bit_cast(unsigned, x);
    unsigned h = u >> 16;
    float r = x - bf2f((short)h);
    unsigned l = __builtin_bit_cast(unsigned, r) >> 16;
    return (h & 0xFFFFu) | (l << 16);
}

// Swizzled offset (in shorts) within a [rows][64 cols] bf16 LDS tile.
__device__ inline int swzS(int row, int b8) {
    return row * 64 + (((b8) * 8) ^ ((row & 7) << 3));
}
// same, addressed by 8B (4-short) granule g4 (0..15)
__device__ inline int swz4(int row, int g4) {
    return row * 64 + ((((g4 >> 1)) * 8) ^ ((row & 7) << 3)) + (g4 & 1) * 4;
}

// ---------------------------------------------------------------------------
// Projection via split-bf16 MFMA: P = X @ W^T + b.  (verified round 10)
// MODE 0: bf16 hi+lo out in [B,H,S,DK]. MODE 1: bf16 V^T out [B,H,DK,S].
// ---------------------------------------------------------------------------
template<int MODE>
__global__ __launch_bounds__(256) void k_projm(
    const float* __restrict__ X, const float* __restrict__ W,
    const float* __restrict__ bias,
    short* __restrict__ outh, short* __restrict__ outl)
{
    __shared__ short WsH[8192], WsL[8192];   // [128 rows][64 k] swizzled
    const int tid = threadIdx.x;
    const int w = tid >> 6, lane = tid & 63;
    const int lr = lane & 15, lg = lane >> 4;
    const int row0 = blockIdx.y * 64;
    const int col0 = blockIdx.x * 128;
    const int xrow = row0 + w * 16 + lr;

    f32x4 acc[8] = {};

    float4 wb[8], ab[4];
#pragma unroll
    for (int i = 0; i < 8; ++i) {
        int idx = tid + 256 * i, wrow = idx >> 4, g4 = idx & 15;
        wb[i] = *(const float4*)&W[(size_t)(col0 + wrow) * ND + g4 * 4];
    }
#pragma unroll
    for (int ks = 0; ks < 2; ++ks) {
        ab[2*ks+0] = *(const float4*)&X[(size_t)xrow * ND + ks * 32 + lg * 8];
        ab[2*ks+1] = *(const float4*)&X[(size_t)xrow * ND + ks * 32 + lg * 8 + 4];
    }

    for (int kc = 0; kc < 8; ++kc) {
        __syncthreads();
#pragma unroll
        for (int i = 0; i < 8; ++i) {
            int idx = tid + 256 * i, wrow = idx >> 4, g4 = idx & 15;
            s16x4 hv, lv;
            unsigned p0 = splitT(wb[i].x), p1 = splitT(wb[i].y);
            unsigned p2 = splitT(wb[i].z), p3 = splitT(wb[i].w);
            hv[0] = (short)p0; lv[0] = (short)(p0 >> 16);
            hv[1] = (short)p1; lv[1] = (short)(p1 >> 16);
            hv[2] = (short)p2; lv[2] = (short)(p2 >> 16);
            hv[3] = (short)p3; lv[3] = (short)(p3 >> 16);
            int off = swz4(wrow, g4);
            *(s16x4*)&WsH[off] = hv;
            *(s16x4*)&WsL[off] = lv;
        }
        __syncthreads();

        short8 ah[2], al[2];
#pragma unroll
        for (int ks = 0; ks < 2; ++ks) {
#pragma unroll
            for (int j = 0; j < 4; ++j) {
                unsigned p = splitT(ab[2*ks][j]);
                ah[ks][j] = (short)p; al[ks][j] = (short)(p >> 16);
            }
#pragma unroll
            for (int j = 0; j < 4; ++j) {
                unsigned p = splitT(ab[2*ks+1][j]);
                ah[ks][4+j] = (short)p; al[ks][4+j] = (short)(p >> 16);
            }
        }

        if (kc < 7) {
            const int kn = (kc + 1) * 64;
#pragma unroll
            for (int i = 0; i < 8; ++i) {
                int idx = tid + 256 * i, wrow = idx >> 4, g4 = idx & 15;
                wb[i] = *(const float4*)&W[(size_t)(col0 + wrow) * ND + kn + g4 * 4];
            }
#pragma unroll
            for (int ks = 0; ks < 2; ++ks) {
                ab[2*ks+0] = *(const float4*)&X[(size_t)xrow * ND + kn + ks * 32 + lg * 8];
                ab[2*ks+1] = *(const float4*)&X[(size_t)xrow * ND + kn + ks * 32 + lg * 8 + 4];
            }
        }

#pragma unroll
        for (int cs = 0; cs < 8; ++cs)
#pragma unroll
            for (int ks = 0; ks < 2; ++ks) {
                short8 fh = *(const short8*)&WsH[swzS(cs * 16 + lr, ks * 4 + lg)];
                short8 fl = *(const short8*)&WsL[swzS(cs * 16 + lr, ks * 4 + lg)];
                acc[cs] = __builtin_amdgcn_mfma_f32_16x16x32_bf16(ah[ks], fh, acc[cs], 0, 0, 0);
                acc[cs] = __builtin_amdgcn_mfma_f32_16x16x32_bf16(ah[ks], fl, acc[cs], 0, 0, 0);
                acc[cs] = __builtin_amdgcn_mfma_f32_16x16x32_bf16(al[ks], fh, acc[cs], 0, 0, 0);
            }
    }

#pragma unroll
    for (int cs = 0; cs < 8; ++cs) {
        int c = col0 + cs * 16 + lr;
        int h_ = c >> 6, dk = c & (NDK - 1);
        float bv = bias[c];
#pragma unroll
        for (int r = 0; r < 4; ++r) {
            int gr = row0 + w * 16 + lg * 4 + r;
            int b_ = gr >> 11, s_ = gr & (NS - 1);
            float x = acc[cs][r] + bv;
            if (MODE == 0) {
                size_t idx = (((size_t)b_ * NH + h_) * NS + s_) * NDK + dk;
                short hb = f2bf(x);
                outh[idx] = hb;
                outl[idx] = f2bf(x - bf2f(hb));
            } else {
                size_t idx = (((size_t)b_ * NH + h_) * NDK + dk) * NS + s_;
                outh[idx] = f2bf(x);
            }
        }
    }
}

// ---------------------------------------------------------------------------
// XCD-clustered remap for 512 blocks = 32 bh x 16 rowtiles(128 rows).
// wg = (bh&7) + 8*rt + 128*(bh>>3)  <->  rt=(wg>>3)&15, bh=(wg&7)+((wg>>7)<<3)
// (bijective for nwg=512; all rowtiles of a bh share one XCD)
// ---------------------------------------------------------------------------
__device__ inline void att_decode2(int wg, int& bh, int& rt) {
    rt = (wg >> 3) & 15;
    bh = (wg & 7) + ((wg >> 7) << 3);
}

// ---------------------------------------------------------------------------
// Fused stats+PV, 32 q-rows per wave (2 row-sets): K/V LDS frag reads are
// shared across both row-sets -> ~2.4x less LDS read traffic per output.
// Register-prefetch pipeline as before.
// ---------------------------------------------------------------------------
__global__ __launch_bounds__(256) void k_pvl(
    const short* __restrict__ qh, const short* __restrict__ ql,
    const short* __restrict__ kh, const short* __restrict__ kl,
    const short* __restrict__ vtb,
    float* __restrict__ iLrow, short* __restrict__ ctxb)
{
    __shared__ short KsH[4096], KsL[4096], Vs[4096];
    __shared__ short plbf[4][32][72];
    const int tid = threadIdx.x;
    const int w = tid >> 6, lane = tid & 63;
    const int lr = lane & 15, lg = lane >> 4;
    int bh, rt;
    att_decode2(blockIdx.x, bh, rt);
    const int row0 = rt * 128 + w * 16;    // set0 rows; set1 = +64
    const size_t base = (size_t)bh * NS * NDK;
    const short* vb = vtb + (size_t)bh * NDK * NS;
    const int srow0 = tid >> 3, sb8 = tid & 7;
    const int srow1 = srow0 + 32;

    short8 ah[2][2], al[2][2];
#pragma unroll
    for (int st = 0; st < 2; ++st)
#pragma unroll
        for (int ks = 0; ks < 2; ++ks) {
            size_t idx = base + (size_t)(row0 + st * 64 + lr) * NDK + ks * 32 + lg * 8;
            ah[st][ks] = *(const short8*)&qh[idx];
            al[st][ks] = *(const short8*)&ql[idx];
        }

    float lsum[2][4] = {};
    f32x4 vacc[2][4] = {};

    short8 nh0, nh1, nl0, nl1, nv0, nv1;
    {
        nh0 = *(const short8*)&kh[base + (size_t)(srow0) * NDK + sb8 * 8];
        nh1 = *(const short8*)&kh[base + (size_t)(srow1) * NDK + sb8 * 8];
        nl0 = *(const short8*)&kl[base + (size_t)(srow0) * NDK + sb8 * 8];
        nl1 = *(const short8*)&kl[base + (size_t)(srow1) * NDK + sb8 * 8];
        nv0 = *(const short8*)&vb[(size_t)srow0 * NS + sb8 * 8];
        nv1 = *(const short8*)&vb[(size_t)srow1 * NS + sb8 * 8];
    }

    for (int c = 0; c < 32; ++c) {
        short8 ch0 = nh0, ch1 = nh1, cl0 = nl0, cl1 = nl1, cv0 = nv0, cv1 = nv1;
        __syncthreads();
        *(short8*)&KsH[swzS(srow0, sb8)] = ch0;
        *(short8*)&KsH[swzS(srow1, sb8)] = ch1;
        *(short8*)&KsL[swzS(srow0, sb8)] = cl0;
        *(short8*)&KsL[swzS(srow1, sb8)] = cl1;
        *(short8*)&Vs[swzS(srow0, sb8)] = cv0;
        *(short8*)&Vs[swzS(srow1, sb8)] = cv1;
        __syncthreads();

        if (c < 31) {
            const int coln = (c + 1) * 64;
            nh0 = *(const short8*)&kh[base + (size_t)(coln + srow0) * NDK + sb8 * 8];
            nh1 = *(const short8*)&kh[base + (size_t)(coln + srow1) * NDK + sb8 * 8];
            nl0 = *(const short8*)&kl[base + (size_t)(coln + srow0) * NDK + sb8 * 8];
            nl1 = *(const short8*)&kl[base + (size_t)(coln + srow1) * NDK + sb8 * 8];
            nv0 = *(const short8*)&vb[(size_t)srow0 * NS + coln + sb8 * 8];
            nv1 = *(const short8*)&vb[(size_t)srow1 * NS + coln + sb8 * 8];
        }

        // QK^T: K frag read ONCE, used by both row-sets
        f32x4 sa[2][4] = {};
#pragma unroll
        for (int cs = 0; cs < 4; ++cs)
#pragma unroll
            for (int ks = 0; ks < 2; ++ks) {
                short8 fh = *(const short8*)&KsH[swzS(cs * 16 + lr, ks * 4 + lg)];
                short8 fl = *(const short8*)&KsL[swzS(cs * 16 + lr, ks * 4 + lg)];
#pragma unroll
                for (int st = 0; st < 2; ++st) {
                    sa[st][cs] = __builtin_amdgcn_mfma_f32_16x16x32_bf16(ah[st][ks], fh, sa[st][cs], 0, 0, 0);
                    sa[st][cs] = __builtin_amdgcn_mfma_f32_16x16x32_bf16(ah[st][ks], fl, sa[st][cs], 0, 0, 0);
                    sa[st][cs] = __builtin_amdgcn_mfma_f32_16x16x32_bf16(al[st][ks], fh, sa[st][cs], 0, 0, 0);
                }
            }

#pragma unroll
        for (int st = 0; st < 2; ++st)
#pragma unroll
            for (int cs = 0; cs < 4; ++cs)
#pragma unroll
                for (int r = 0; r < 4; ++r) {
                    float e = __expf(fminf(sa[st][cs][r], SCLAMP));
                    lsum[st][r] += e;
                    plbf[w][st * 16 + lg * 4 + r][cs * 16 + lr] = f2bf(e);
                }

        // PV: V frag read ONCE per (k2,d), used by both row-sets
#pragma unroll
        for (int k2 = 0; k2 < 2; ++k2) {
            short8 pa0 = *(const short8*)&plbf[w][lr][k2 * 32 + lg * 8];
            short8 pa1 = *(const short8*)&plbf[w][16 + lr][k2 * 32 + lg * 8];
#pragma unroll
            for (int d = 0; d < 4; ++d) {
                short8 vf = *(const short8*)&Vs[swzS(d * 16 + lr, k2 * 4 + lg)];
                vacc[0][d] = __builtin_amdgcn_mfma_f32_16x16x32_bf16(pa0, vf, vacc[0][d], 0, 0, 0);
                vacc[1][d] = __builtin_amdgcn_mfma_f32_16x16x32_bf16(pa1, vf, vacc[1][d], 0, 0, 0);
            }
        }
    }

#pragma unroll
    for (int st = 0; st < 2; ++st)
#pragma unroll
        for (int r = 0; r < 4; ++r)
#pragma unroll
            for (int off = 1; off < 16; off <<= 1)
                lsum[st][r] += __shfl_xor(lsum[st][r], off);

    float iL[2][4];
#pragma unroll
    for (int st = 0; st < 2; ++st)
#pragma unroll
        for (int r = 0; r < 4; ++r) iL[st][r] = 1.0f / lsum[st][r];
    if (lr == 0) {
#pragma unroll
        for (int st = 0; st < 2; ++st)
#pragma unroll
            for (int r = 0; r < 4; ++r)
                iLrow[(size_t)bh * NS + row0 + st * 64 + lg * 4 + r] = iL[st][r];
    }
    const int b_ = bh >> 3, h_ = bh & 7;
#pragma unroll
    for (int st = 0; st < 2; ++st)
#pragma unroll
        for (int d = 0; d < 4; ++d)
#pragma unroll
            for (int r = 0; r < 4; ++r) {
                int row = row0 + st * 64 + lg * 4 + r;
                ctxb[((size_t)b_ * NS + row) * ND + h_ * NDK + d * 16 + lr] =
                    f2bf(vacc[st][d][r] * iL[st][r]);
            }
}

// ---------------------------------------------------------------------------
// Attn writer, 32 q-rows per wave: K frag reads shared by 2 row-sets.
// Recomputes scores (identical MFMA sequence), p = exp(min(s,80))*iL.
// ---------------------------------------------------------------------------
__global__ __launch_bounds__(256) void k_attn_write(
    const short* __restrict__ qh, const short* __restrict__ ql,
    const short* __restrict__ kh, const short* __restrict__ kl,
    const float* __restrict__ iLrow, float* __restrict__ attn)
{
    __shared__ short KsH[4096], KsL[4096];
    const int tid = threadIdx.x;
    const int w = tid >> 6, lane = tid & 63;
    const int lr = lane & 15, lg = lane >> 4;
    int bh, rt;
    att_decode2(blockIdx.x, bh, rt);
    const int row0 = rt * 128 + w * 16;
    const size_t base = (size_t)bh * NS * NDK;
    float* ab = attn + (size_t)bh * NS * NS;
    const int srow0 = tid >> 3, sb8 = tid & 7;
    const int srow1 = srow0 + 32;

    short8 ah[2][2], al[2][2];
#pragma unroll
    for (int st = 0; st < 2; ++st)
#pragma unroll
        for (int ks = 0; ks < 2; ++ks) {
            size_t idx = base + (size_t)(row0 + st * 64 + lr) * NDK + ks * 32 + lg * 8;
            ah[st][ks] = *(const short8*)&qh[idx];
            al[st][ks] = *(const short8*)&ql[idx];
        }
    float iLr[2][4];
#pragma unroll
    for (int st = 0; st < 2; ++st)
#pragma unroll
        for (int r = 0; r < 4; ++r)
            iLr[st][r] = iLrow[(size_t)bh * NS + row0 + st * 64 + lg * 4 + r];

    short8 nh0, nh1, nl0, nl1;
    {
        nh0 = *(const short8*)&kh[base + (size_t)(srow0) * NDK + sb8 * 8];
        nh1 = *(const short8*)&kh[base + (size_t)(srow1) * NDK + sb8 * 8];
        nl0 = *(const short8*)&kl[base + (size_t)(srow0) * NDK + sb8 * 8];
        nl1 = *(const short8*)&kl[base + (size_t)(srow1) * NDK + sb8 * 8];
    }

    for (int c = 0; c < 32; ++c) {
        short8 ch0 = nh0, ch1 = nh1, cl0 = nl0, cl1 = nl1;
        __syncthreads();
        *(short8*)&KsH[swzS(srow0, sb8)] = ch0;
        *(short8*)&KsH[swzS(srow1, sb8)] = ch1;
        *(short8*)&KsL[swzS(srow0, sb8)] = cl0;
        *(short8*)&KsL[swzS(srow1, sb8)] = cl1;
        __syncthreads();

        if (c < 31) {
            const int coln = (c + 1) * 64;
            nh0 = *(const short8*)&kh[base + (size_t)(coln + srow0) * NDK + sb8 * 8];
            nh1 = *(const short8*)&kh[base + (size_t)(coln + srow1) * NDK + sb8 * 8];
            nl0 = *(const short8*)&kl[base + (size_t)(coln + srow0) * NDK + sb8 * 8];
            nl1 = *(const short8*)&kl[base + (size_t)(coln + srow1) * NDK + sb8 * 8];
        }

        const int col0 = c * 64;
        f32x4 sa[2][4] = {};
#pragma unroll
        for (int cs = 0; cs < 4; ++cs)
#pragma unroll
            for (int ks = 0; ks < 2; ++ks) {
                short8 fh = *(const short8*)&KsH[swzS(cs * 16 + lr, ks * 4 + lg)];
                short8 fl = *(const short8*)&KsL[swzS(cs * 16 + lr, ks * 4 + lg)];
#pragma unroll
                for (int st = 0; st < 2; ++st) {
                    sa[st][cs] = __builtin_amdgcn_mfma_f32_16x16x32_bf16(ah[st][ks], fh, sa[st][cs], 0, 0, 0);
                    sa[st][cs] = __builtin_amdgcn_mfma_f32_16x16x32_bf16(ah[st][ks], fl, sa[st][cs], 0, 0, 0);
                    sa[st][cs] = __builtin_amdgcn_mfma_f32_16x16x32_bf16(al[st][ks], fh, sa[st][cs], 0, 0, 0);
                }
            }

#pragma unroll
        for (int st = 0; st < 2; ++st)
#pragma unroll
            for (int cs = 0; cs < 4; ++cs)
#pragma unroll
                for (int r = 0; r < 4; ++r) {
                    float p = __expf(fminf(sa[st][cs][r], SCLAMP)) * iLr[st][r];
                    ab[(size_t)(row0 + st * 64 + lg * 4 + r) * NS + col0 + cs * 16 + lr] = p;
                }
    }
}

// ---------------------------------------------------------------------------
// Out-projection via MFMA: out = ctx_bf16 @ Wo^T + bo + residual (f32 out).
// ---------------------------------------------------------------------------
__global__ __launch_bounds__(256) void k_outproj_m(
    const short* __restrict__ Xc, const float* __restrict__ W,
    const float* __restrict__ bias, const float* __restrict__ Qin,
    float* __restrict__ out)
{
    __shared__ short WsH[8192], WsL[8192];   // [128 rows][64 k] swizzled
    const int tid = threadIdx.x;
    const int w = tid >> 6, lane = tid & 63;
    const int lr = lane & 15, lg = lane >> 4;
    const int row0 = blockIdx.y * 64;
    const int col0 = blockIdx.x * 128;
    const int xrow = row0 + w * 16 + lr;

    f32x4 acc[8] = {};

    float4 wb[8];
    short8 abn[2];
#pragma unroll
    for (int i = 0; i < 8; ++i) {
        int idx = tid + 256 * i, wrow = idx >> 4, g4 = idx & 15;
        wb[i] = *(const float4*)&W[(size_t)(col0 + wrow) * ND + g4 * 4];
    }
#pragma unroll
    for (int ks = 0; ks < 2; ++ks)
        abn[ks] = *(const short8*)&Xc[(size_t)xrow * ND + ks * 32 + lg * 8];

    for (int kc = 0; kc < 8; ++kc) {
        __syncthreads();
#pragma unroll
        for (int i = 0; i < 8; ++i) {
            int idx = tid + 256 * i, wrow = idx >> 4, g4 = idx & 15;
            s16x4 hv, lv;
            unsigned p0 = splitT(wb[i].x), p1 = splitT(wb[i].y);
            unsigned p2 = splitT(wb[i].z), p3 = splitT(wb[i].w);
            hv[0] = (short)p0; lv[0] = (short)(p0 >> 16);
            hv[1] = (short)p1; lv[1] = (short)(p1 >> 16);
            hv[2] = (short)p2; lv[2] = (short)(p2 >> 16);
            hv[3] = (short)p3; lv[3] = (short)(p3 >> 16);
            int off = swz4(wrow, g4);
            *(s16x4*)&WsH[off] = hv;
            *(s16x4*)&WsL[off] = lv;
        }
        __syncthreads();

        short8 ah[2] = { abn[0], abn[1] };

        if (kc < 7) {
            const int kn = (kc + 1) * 64;
#pragma unroll
            for (int i = 0; i < 8; ++i) {
                int idx = tid + 256 * i, wrow = idx >> 4, g4 = idx & 15;
                wb[i] = *(const float4*)&W[(size_t)(col0 + wrow) * ND + kn + g4 * 4];
            }
#pragma unroll
            for (int ks = 0; ks < 2; ++ks)
                abn[ks] = *(const short8*)&Xc[(size_t)xrow * ND + kn + ks * 32 + lg * 8];
        }

#pragma unroll
        for (int cs = 0; cs < 8; ++cs)
#pragma unroll
            for (int ks = 0; ks < 2; ++ks) {
                short8 fh = *(const short8*)&WsH[swzS(cs * 16 + lr, ks * 4 + lg)];
                short8 fl = *(const short8*)&WsL[swzS(cs * 16 + lr, ks * 4 + lg)];
                acc[cs] = __builtin_amdgcn_mfma_f32_16x16x32_bf16(ah[ks], fh, acc[cs], 0, 0, 0);
                acc[cs] = __builtin_amdgcn_mfma_f32_16x16x32_bf16(ah[ks], fl, acc[cs], 0, 0, 0);
            }
    }

#pragma unroll
    for (int cs = 0; cs < 8; ++cs) {
        int c = col0 + cs * 16 + lr;
        float bv = bias[c];
#pragma unroll
        for (int r = 0; r < 4; ++r) {
            int gr = row0 + w * 16 + lg * 4 + r;
            float res = Qin[(size_t)gr * ND + c];
            out[(size_t)gr * ND + c] = acc[cs][r] + bv + res;
        }
    }
}

// ---------------------------------------------------------------------------
// In-place LayerNorm over last dim (512).
// ---------------------------------------------------------------------------
__global__ __launch_bounds__(256) void k_ln(
    float* __restrict__ out, const float* __restrict__ gamma,
    const float* __restrict__ beta)
{
    const int tid = threadIdx.x;
    float* p = out + (size_t)blockIdx.x * ND;
    float2 v = *(const float2*)&p[tid * 2];

    float s = v.x + v.y;
#pragma unroll
    for (int off = 32; off > 0; off >>= 1) s += __shfl_xor(s, off);
    __shared__ float red1[4];
    __shared__ float red2[4];
    if ((tid & 63) == 0) red1[tid >> 6] = s;
    __syncthreads();
    const float mu = (red1[0] + red1[1] + red1[2] + red1[3]) * (1.0f / ND);

    float dx = v.x - mu, dy = v.y - mu;
    float q = dx * dx + dy * dy;
#pragma unroll
    for (int off = 32; off > 0; off >>= 1) q += __shfl_xor(q, off);
    if ((tid & 63) == 0) red2[tid >> 6] = q;
    __syncthreads();
    const float var = (red2[0] + red2[1] + red2[2] + red2[3]) * (1.0f / ND);
    const float inv = rsqrtf(var + LN_EPS);

    float2 g = *(const float2*)&gamma[tid * 2];
    float2 be = *(const float2*)&beta[tid * 2];
    float2 o = { dx * inv * g.x + be.x, dy * inv * g.y + be.y };
    *(float2*)&p[tid * 2] = o;
}

// ---------------------------------------------------------------------------
extern "C" void kernel_launch(void* const* d_in, const int* in_sizes, int n_in,
                              void* d_out, int out_size, void* d_ws, size_t ws_size,
                              hipStream_t stream)
{
    const float* Q    = (const float*)d_in[0];
    const float* K    = (const float*)d_in[1];
    const float* V    = (const float*)d_in[2];
    const float* Wq   = (const float*)d_in[3];
    const float* bq   = (const float*)d_in[4];
    const float* Wk   = (const float*)d_in[5];
    const float* bk   = (const float*)d_in[6];
    const float* Wv   = (const float*)d_in[7];
    const float* bv   = (const float*)d_in[8];
    const float* Wo   = (const float*)d_in[9];
    const float* bo   = (const float*)d_in[10];
    const float* gam  = (const float*)d_in[11];
    const float* bet  = (const float*)d_in[12];

    float* out  = (float*)d_out;                       // [NB*NS*ND]
    float* attn = out + (size_t)NB * NS * ND;          // [NB*NH*NS*NS]

    const size_t QKV = (size_t)NB * NH * NS * NDK;     // 4.19M elements
    short* qh   = (short*)d_ws;
    short* ql   = qh + QKV;
    short* kh   = ql + QKV;
    short* kl   = kh + QKV;
    short* vtb  = kl + QKV;
    short* ctxb = vtb + QKV;
    float* iLrow = (float*)(ctxb + QKV);               // [32][2048]

    dim3 blk(256);

    dim3 gP(ND / 128, (NB * NS) / 64);                 // (4, 128)
    k_projm<0><<<gP, blk, 0, stream>>>(Q, Wq, bq, qh, ql);
    k_projm<0><<<gP, blk, 0, stream>>>(K, Wk, bk, kh, kl);
    k_projm<1><<<gP, blk, 0, stream>>>(V, Wv, bv, vtb, (short*)nullptr);

    dim3 gAtt((NS / 128) * NB * NH);                   // 512, XCD-remapped
    k_pvl<<<gAtt, blk, 0, stream>>>(qh, ql, kh, kl, vtb, iLrow, ctxb);
    k_attn_write<<<gAtt, blk, 0, stream>>>(qh, ql, kh, kl, iLrow, attn);

    dim3 gO(ND / 128, (NB * NS) / 64);                 // (4, 128)
    k_outproj_m<<<gO, blk, 0, stream>>>(ctxb, Wo, bo, Q, out);

    k_ln<<<dim3(NB * NS), blk, 0, stream>>>(out, gam, bet);
}